// Round 4
// baseline (2312.284 us; speedup 1.0000x reference)
//
#include <hip/hip_runtime.h>

#define WAVE 64

// ---------------- CSR build ----------------

__global__ void k_count(const int* __restrict__ dst, const int* __restrict__ typ,
                        int* __restrict__ cnt4, int E) {
    int e = blockIdx.x * 256 + threadIdx.x;
    if (e < E) atomicAdd(&cnt4[dst[e] * 4 + typ[e]], 1);
}

// exclusive scan over M=4N elems; 1024 elems/block
__global__ void k_scan1(const int* __restrict__ in, int* __restrict__ out,
                        int* __restrict__ bsum, int M) {
    __shared__ int s[256];
    int t = threadIdx.x;
    int base = blockIdx.x * 1024 + t * 4;
    int v0 = (base + 0 < M) ? in[base + 0] : 0;
    int v1 = (base + 1 < M) ? in[base + 1] : 0;
    int v2 = (base + 2 < M) ? in[base + 2] : 0;
    int v3 = (base + 3 < M) ? in[base + 3] : 0;
    int ts = v0 + v1 + v2 + v3;
    s[t] = ts;
    __syncthreads();
    for (int off = 1; off < 256; off <<= 1) {
        int x = (t >= off) ? s[t - off] : 0;
        __syncthreads();
        s[t] += x;
        __syncthreads();
    }
    int excl = (t == 0) ? 0 : s[t - 1];
    if (t == 255) bsum[blockIdx.x] = s[255];
    if (base + 0 < M) out[base + 0] = excl;
    if (base + 1 < M) out[base + 1] = excl + v0;
    if (base + 2 < M) out[base + 2] = excl + v0 + v1;
    if (base + 3 < M) out[base + 3] = excl + v0 + v1 + v2;
}

__global__ void k_scan2(const int* __restrict__ bsum, int* __restrict__ boff, int nb) {
    __shared__ int s[512];
    int t = threadIdx.x;
    s[t] = (t < nb) ? bsum[t] : 0;
    __syncthreads();
    for (int off = 1; off < 512; off <<= 1) {
        int x = (t >= off) ? s[t - off] : 0;
        __syncthreads();
        s[t] += x;
        __syncthreads();
    }
    if (t < nb) boff[t] = (t == 0) ? 0 : s[t - 1];
}

__global__ void k_scan3(int* __restrict__ out, const int* __restrict__ boff, int M, int E) {
    int i = blockIdx.x * 256 + threadIdx.x;
    if (i < M) out[i] += boff[i >> 10];
    else if (i == M) out[M] = E;
}

// pack: src (17b) | rel (2b) | dst&63 (6b)
__global__ void k_fill(const int* __restrict__ src, const int* __restrict__ dst,
                       const int* __restrict__ typ, const int* __restrict__ start4,
                       int* __restrict__ cursor4, int* __restrict__ elist, int E) {
    int e = blockIdx.x * 256 + threadIdx.x;
    if (e < E) {
        int d = dst[e], t = typ[e];
        int seg = d * 4 + t;
        int p = atomicAdd(&cursor4[seg], 1);
        elist[start4[seg] + p] = src[e] | (t << 17) | ((d & 63) << 19);
    }
}

// ---------------- weight concat: Wcat[l][k<320][h<64] = [W_r rows | root rows] ----------------

__global__ void k_wcat(const float* __restrict__ W1, const float* __restrict__ root1,
                       const float* __restrict__ Wl, const float* __restrict__ rootl,
                       float* __restrict__ Wcat) {
    int idx = blockIdx.x * 256 + threadIdx.x;
    const int TOT = 3 * 320 * 64;
    if (idx >= TOT) return;
    int l = idx / (320 * 64);
    int rem = idx - l * (320 * 64);
    int k = rem >> 6;
    int h = rem & 63;
    float v;
    if (k < 256) {
        v = (l == 0) ? W1[k * 64 + h] : Wl[(l - 1) * 16384 + k * 64 + h];
    } else {
        v = (l == 0) ? root1[(k - 256) * 64 + h] : rootl[(l - 1) * 4096 + (k - 256) * 64 + h];
    }
    Wcat[idx] = v;
}

// ---------------- fused RGCN conv layer ----------------
// A-tile LDS layout: elem (k, n) at k*64 + (n ^ ((k&7)<<2)).
#define SWZ(k, n) ((k) * 64 + ((n) ^ (((k) & 7) << 2)))

#define EDGE_BODY(w)                                                   \
    {                                                                  \
        int s_  = (w) & 0x1FFFF;                                       \
        int r_  = ((w) >> 17) & 3;                                     \
        int nl_ = ((w) >> 19) & 63;                                    \
        float v_ = hin[(size_t)s_ * 64 + lane];                        \
        atomicAdd(&A[SWZ(r_ * 64 + lane, nl_)], v_);                   \
    }

__global__ __launch_bounds__(256, 2) void k_conv(
        const float* __restrict__ hin, float* __restrict__ hout,
        const int* __restrict__ elist, const int* __restrict__ start4,
        const float* __restrict__ Wc, const float* __restrict__ bias, int nN) {
    extern __shared__ float A[];  // 320*64 floats = 80 KB
    const int tid = threadIdx.x;
    const int lane = tid & 63;
    const int wv = tid >> 6;
    const int tile = blockIdx.x * 64;
    const int nend = (tile + 64 < nN) ? (tile + 64) : nN;

    // zero A-tile
    const float4 z4 = make_float4(0.f, 0.f, 0.f, 0.f);
#pragma unroll
    for (int i = 0; i < 20; ++i)
        *reinterpret_cast<float4*>(&A[(tid + i * 256) * 4]) = z4;
    __syncthreads();

    // phase 1: flat edge loop over the block's contiguous CSR range.
    // Waves take 64-edge groups round-robin; one coalesced load per group,
    // scalar (readlane) decode, gather + LDS float atomic accumulate.
    const int e_lo = start4[4 * tile];
    const int e_hi = start4[4 * nend];
    for (int base = e_lo + wv * 64; base < e_hi; base += 256) {
        int nrem = e_hi - base;
        int idx = base + ((lane < nrem) ? lane : 0);
        int w64 = elist[idx];
        if (nrem >= 64) {
#pragma unroll
            for (int u = 0; u < 64; ++u) {
                int w = __builtin_amdgcn_readlane(w64, u);
                EDGE_BODY(w);
            }
        } else {
            for (int u = 0; u < nrem; ++u) {
                int w = __builtin_amdgcn_readlane(w64, u);
                EDGE_BODY(w);
            }
        }
    }
    __syncthreads();

    // phase 1.5a: self rows (k = 256..319), coalesced global read
    {
        int nl = tid >> 2;
        int f0 = (tid & 3) * 16;
        int n = tile + nl;
        if (n < nN) {
#pragma unroll
            for (int j = 0; j < 16; j += 4) {
                float4 v = *reinterpret_cast<const float4*>(&hin[(size_t)n * 64 + f0 + j]);
                A[SWZ(256 + f0 + j + 0, nl)] = v.x;
                A[SWZ(256 + f0 + j + 1, nl)] = v.y;
                A[SWZ(256 + f0 + j + 2, nl)] = v.z;
                A[SWZ(256 + f0 + j + 3, nl)] = v.w;
            }
        }
    }
    // phase 1.5b: scale aggregates to means
    {
        int n = tid & 63;
        int r = tid >> 6;
        int gn = tile + n;
        if (gn < nN) {
            int c0 = start4[gn * 4 + r];
            int c1 = start4[gn * 4 + r + 1];
            float inv = (c1 > c0) ? 1.0f / (float)(c1 - c0) : 0.f;
#pragma unroll 8
            for (int f = 0; f < 64; ++f) {
                A[SWZ(r * 64 + f, n)] *= inv;
            }
        }
    }
    __syncthreads();

    // phase 2: C[64n x 64h] = A[320 x 64n]^T * Wc[320 x 64h]; 4x4 per thread
    const int n0 = (tid & 15) << 2;
    const int h0 = (tid >> 4) << 2;
    float cc[4][4];
#pragma unroll
    for (int i = 0; i < 4; ++i)
#pragma unroll
        for (int j = 0; j < 4; ++j) cc[i][j] = 0.f;

#pragma unroll 8
    for (int k = 0; k < 320; ++k) {
        const float4 a = *reinterpret_cast<const float4*>(&A[k * 64 + (n0 ^ ((k & 7) << 2))]);
        const float4 w = *reinterpret_cast<const float4*>(&Wc[k * 64 + h0]);
        cc[0][0] += a.x * w.x; cc[0][1] += a.x * w.y; cc[0][2] += a.x * w.z; cc[0][3] += a.x * w.w;
        cc[1][0] += a.y * w.x; cc[1][1] += a.y * w.y; cc[1][2] += a.y * w.z; cc[1][3] += a.y * w.w;
        cc[2][0] += a.z * w.x; cc[2][1] += a.z * w.y; cc[2][2] += a.z * w.z; cc[2][3] += a.z * w.w;
        cc[3][0] += a.w * w.x; cc[3][1] += a.w * w.y; cc[3][2] += a.w * w.z; cc[3][3] += a.w * w.w;
    }

    const float b0 = bias[h0 + 0], b1 = bias[h0 + 1], b2 = bias[h0 + 2], b3 = bias[h0 + 3];
#pragma unroll
    for (int i = 0; i < 4; ++i) {
        int n = tile + n0 + i;
        if (n < nN) {
            float4 o;
            o.x = fmaxf(cc[i][0] + b0, 0.f);
            o.y = fmaxf(cc[i][1] + b1, 0.f);
            o.z = fmaxf(cc[i][2] + b2, 0.f);
            o.w = fmaxf(cc[i][3] + b3, 0.f);
            *reinterpret_cast<float4*>(&hout[n * 64 + h0]) = o;
        }
    }
}

// ---------------- pooling ----------------

__global__ void k_pool(const float* __restrict__ h, const int* __restrict__ batch,
                       float* __restrict__ g_sum, int nN) {
    int gid = blockIdx.x * 256 + threadIdx.x;
    int hi = gid & 63;
    int n0 = (gid >> 6) * 8;
    if (n0 >= nN) return;
    int end = n0 + 8;
    if (end > nN) end = nN;
    float acc = 0.f;
    int cur = batch[n0];
    for (int n = n0; n < end; ++n) {
        int b = batch[n];
        if (b != cur) {
            atomicAdd(&g_sum[cur * 64 + hi], acc);
            acc = 0.f;
            cur = b;
        }
        acc += h[n * 64 + hi];
    }
    atomicAdd(&g_sum[cur * 64 + hi], acc);
}

__global__ void k_cntg(const int* __restrict__ batch, float* __restrict__ cnt_g, int nN) {
    int n = blockIdx.x * 256 + threadIdx.x;
    if (n < nN) atomicAdd(&cnt_g[batch[n]], 1.0f);
}

// ---------------- final MLP: g -> relu(g@w1+b1) -> @w2+b2 ----------------

__global__ void k_mlp(const float* __restrict__ g_sum, const float* __restrict__ cnt_g,
                      const float* __restrict__ w1, const float* __restrict__ b1,
                      const float* __restrict__ w2, const float* __restrict__ b2,
                      float* __restrict__ out) {
    __shared__ float sg[64];
    __shared__ float sh[64];
    int g = blockIdx.x;
    int h = threadIdx.x;
    float c = cnt_g[g];
    sg[h] = g_sum[g * 64 + h] / fmaxf(c, 1.0f);
    __syncthreads();
    float acc = b1[h];
#pragma unroll
    for (int f = 0; f < 64; ++f) acc += sg[f] * w1[f * 64 + h];
    sh[h] = fmaxf(acc, 0.f);
    __syncthreads();
    if (h < 10) {
        float o = b2[h];
#pragma unroll
        for (int f = 0; f < 64; ++f) o += sh[f] * w2[f * 10 + h];
        out[g * 10 + h] = o;
    }
}

// ---------------- launch ----------------

extern "C" void kernel_launch(void* const* d_in, const int* in_sizes, int n_in,
                              void* d_out, int out_size, void* d_ws, size_t ws_size,
                              hipStream_t stream) {
    const float* x     = (const float*)d_in[0];
    const int*   ei    = (const int*)d_in[1];
    const int*   et    = (const int*)d_in[2];
    const int*   batch = (const int*)d_in[3];
    const float* W1    = (const float*)d_in[4];
    const float* root1 = (const float*)d_in[5];
    const float* b1    = (const float*)d_in[6];
    const float* Wl    = (const float*)d_in[7];
    const float* rootl = (const float*)d_in[8];
    const float* bl    = (const float*)d_in[9];
    const float* l1w   = (const float*)d_in[10];
    const float* l1b   = (const float*)d_in[11];
    const float* l2w   = (const float*)d_in[12];
    const float* l2b   = (const float*)d_in[13];
    float* out = (float*)d_out;

    const int N = in_sizes[3];
    const int E = in_sizes[2];
    const int G = out_size / 10;
    const int M = 4 * N;

    const int* src = ei;
    const int* dst = ei + E;

    // workspace carve-out (512B aligned)
    char* base = (char*)d_ws;
    size_t off = 0;
    auto carve = [&](size_t bytes) {
        char* p = base + off;
        off = (off + bytes + 511) & ~(size_t)511;
        return p;
    };
    int*   cnt4    = (int*)carve((size_t)M * 4);
    int*   start4  = (int*)carve((size_t)(M + 1) * 4);
    int*   cursor4 = (int*)carve((size_t)M * 4);
    int*   elist   = (int*)carve((size_t)E * 4);
    int*   bsum    = (int*)carve(512 * 4);
    int*   boff    = (int*)carve(512 * 4);
    float* Wcat    = (float*)carve((size_t)3 * 320 * 64 * 4);
    float* h_a     = (float*)carve((size_t)N * 64 * 4);
    float* h_b     = (float*)carve((size_t)N * 64 * 4);
    float* g_sum   = (float*)carve((size_t)G * 64 * 4);
    float* cnt_g   = (float*)carve((size_t)G * 4);
    (void)ws_size;

    hipMemsetAsync(cnt4, 0, (size_t)M * 4, stream);
    hipMemsetAsync(cursor4, 0, (size_t)M * 4, stream);
    hipMemsetAsync(g_sum, 0, (size_t)G * 64 * 4, stream);
    hipMemsetAsync(cnt_g, 0, (size_t)G * 4, stream);

    k_count<<<(E + 255) / 256, 256, 0, stream>>>(dst, et, cnt4, E);

    int nb = (M + 1023) / 1024;
    k_scan1<<<nb, 256, 0, stream>>>(cnt4, start4, bsum, M);
    k_scan2<<<1, 512, 0, stream>>>(bsum, boff, nb);
    k_scan3<<<(M + 1 + 255) / 256, 256, 0, stream>>>(start4, boff, M, E);
    k_fill<<<(E + 255) / 256, 256, 0, stream>>>(src, dst, et, start4, cursor4, elist, E);

    k_wcat<<<(3 * 320 * 64 + 255) / 256, 256, 0, stream>>>(W1, root1, Wl, rootl, Wcat);

    static bool attr_set = false;
    if (!attr_set) {
        hipFuncSetAttribute((const void*)k_conv,
                            hipFuncAttributeMaxDynamicSharedMemorySize, 320 * 64 * 4);
        attr_set = true;
    }

    const int cb = (N + 63) / 64;
    const size_t lds = 320 * 64 * 4;
    k_conv<<<cb, 256, lds, stream>>>(x,   h_a, elist, start4, Wcat,                b1,      N);
    k_conv<<<cb, 256, lds, stream>>>(h_a, h_b, elist, start4, Wcat + 320 * 64,     bl,      N);
    k_conv<<<cb, 256, lds, stream>>>(h_b, h_a, elist, start4, Wcat + 2 * 320 * 64, bl + 64, N);

    k_pool<<<(((N + 7) / 8) * 64 + 255) / 256, 256, 0, stream>>>(h_a, batch, g_sum, N);
    k_cntg<<<(N + 255) / 256, 256, 0, stream>>>(batch, cnt_g, N);
    k_mlp<<<G, 64, 0, stream>>>(g_sum, cnt_g, l1w, l1b, l2w, l2b, out);
}

// Round 5
// 835.347 us; speedup vs baseline: 2.7681x; 2.7681x over previous
//
#include <hip/hip_runtime.h>

#define TILE 32
#define KDIM 320

// ---------------- CSR build ----------------

__global__ void k_count(const int* __restrict__ dst, const int* __restrict__ typ,
                        int* __restrict__ cnt4, int E) {
    int e = blockIdx.x * 256 + threadIdx.x;
    if (e < E) atomicAdd(&cnt4[dst[e] * 4 + typ[e]], 1);
}

// exclusive scan over M=4N elems; 1024 elems/block
__global__ void k_scan1(const int* __restrict__ in, int* __restrict__ out,
                        int* __restrict__ bsum, int M) {
    __shared__ int s[256];
    int t = threadIdx.x;
    int base = blockIdx.x * 1024 + t * 4;
    int v0 = (base + 0 < M) ? in[base + 0] : 0;
    int v1 = (base + 1 < M) ? in[base + 1] : 0;
    int v2 = (base + 2 < M) ? in[base + 2] : 0;
    int v3 = (base + 3 < M) ? in[base + 3] : 0;
    int ts = v0 + v1 + v2 + v3;
    s[t] = ts;
    __syncthreads();
    for (int off = 1; off < 256; off <<= 1) {
        int x = (t >= off) ? s[t - off] : 0;
        __syncthreads();
        s[t] += x;
        __syncthreads();
    }
    int excl = (t == 0) ? 0 : s[t - 1];
    if (t == 255) bsum[blockIdx.x] = s[255];
    if (base + 0 < M) out[base + 0] = excl;
    if (base + 1 < M) out[base + 1] = excl + v0;
    if (base + 2 < M) out[base + 2] = excl + v0 + v1;
    if (base + 3 < M) out[base + 3] = excl + v0 + v1 + v2;
}

__global__ void k_scan2(const int* __restrict__ bsum, int* __restrict__ boff, int nb) {
    __shared__ int s[512];
    int t = threadIdx.x;
    s[t] = (t < nb) ? bsum[t] : 0;
    __syncthreads();
    for (int off = 1; off < 512; off <<= 1) {
        int x = (t >= off) ? s[t - off] : 0;
        __syncthreads();
        s[t] += x;
        __syncthreads();
    }
    if (t < nb) boff[t] = (t == 0) ? 0 : s[t - 1];
}

__global__ void k_scan3(int* __restrict__ out, const int* __restrict__ boff, int M, int E) {
    int i = blockIdx.x * 256 + threadIdx.x;
    if (i < M) out[i] += boff[i >> 10];
    else if (i == M) out[M] = E;
}

__global__ void k_fill(const int* __restrict__ src, const int* __restrict__ dst,
                       const int* __restrict__ typ, const int* __restrict__ start4,
                       int* __restrict__ cursor4, int* __restrict__ elist, int E) {
    int e = blockIdx.x * 256 + threadIdx.x;
    if (e < E) {
        int seg = dst[e] * 4 + typ[e];
        int p = atomicAdd(&cursor4[seg], 1);
        elist[start4[seg] + p] = src[e];
    }
}

// ---------------- weight concat: Wcat[l][k<320][h<64] = [W_r rows | root rows] ----------------

__global__ void k_wcat(const float* __restrict__ W1, const float* __restrict__ root1,
                       const float* __restrict__ Wl, const float* __restrict__ rootl,
                       float* __restrict__ Wcat) {
    int idx = blockIdx.x * 256 + threadIdx.x;
    const int TOT = 3 * 320 * 64;
    if (idx >= TOT) return;
    int l = idx / (320 * 64);
    int rem = idx - l * (320 * 64);
    int k = rem >> 6;
    int h = rem & 63;
    float v;
    if (k < 256) {
        v = (l == 0) ? W1[k * 64 + h] : Wl[(l - 1) * 16384 + k * 64 + h];
    } else {
        v = (l == 0) ? root1[(k - 256) * 64 + h] : rootl[(l - 1) * 4096 + (k - 256) * 64 + h];
    }
    Wcat[idx] = v;
}

// ---------------- fused RGCN conv layer ----------------
// A2 layout: node-major, A2[n*320 + (k ^ ((n&7)<<2))].
// Phase-1 writes: contiguous 64-float runs (2-way banks, free).
// Phase-2 reads: float4 along k; XOR has no bits 0-1 so 4-contiguity/16B-align hold.

__global__ __launch_bounds__(256, 4) void k_conv(
        const float* __restrict__ hin, float* __restrict__ hout,
        const int* __restrict__ elist, const int* __restrict__ start4,
        const float* __restrict__ Wc, const float* __restrict__ bias, int nN) {
    __shared__ float A2[TILE * KDIM];  // 40 KB -> 4 blocks/CU
    const int tid = threadIdx.x;
    const int lane = tid & 63;
    const int wv = tid >> 6;
    const int tile = blockIdx.x * TILE;

    // phase 1: each wave aggregates 8 nodes; flat edge loop, unroll x8,
    // suffix-sum relation routing (seg_r = S_r - S_{r+1}).
    for (int jj = 0; jj < 8; ++jj) {
        int nl = wv * 8 + jj;
        int n = tile + nl;
        if (n >= nN) break;
        const int* s4 = start4 + n * 4;
        int e0 = s4[0], e1 = s4[1], e2 = s4[2], e3 = s4[3], e4 = s4[4];
        float self = hin[(size_t)n * 64 + lane];
        float S0 = 0.f, S1 = 0.f, S2 = 0.f, S3 = 0.f;
        for (int p = e0; p < e4; p += 8) {
            int qidx[8];
#pragma unroll
            for (int u = 0; u < 8; ++u) {
                int q = p + u;
                qidx[u] = elist[(q < e4) ? q : e0];
            }
            float v[8];
#pragma unroll
            for (int u = 0; u < 8; ++u)
                v[u] = hin[(size_t)qidx[u] * 64 + lane];
#pragma unroll
            for (int u = 0; u < 8; ++u) {
                int q = p + u;
                float t = (q < e4) ? v[u] : 0.f;
                S0 += t;
                S1 += (q >= e1) ? t : 0.f;
                S2 += (q >= e2) ? t : 0.f;
                S3 += (q >= e3) ? t : 0.f;
            }
        }
        int c0 = e1 - e0, c1 = e2 - e1, c2 = e3 - e2, c3 = e4 - e3;
        float a0 = (S0 - S1) * ((c0 > 0) ? 1.0f / (float)c0 : 0.f);
        float a1 = (S1 - S2) * ((c1 > 0) ? 1.0f / (float)c1 : 0.f);
        float a2 = (S2 - S3) * ((c2 > 0) ? 1.0f / (float)c2 : 0.f);
        float a3 = S3 * ((c3 > 0) ? 1.0f / (float)c3 : 0.f);
        float* Arow = &A2[nl * KDIM];
        const int lx = lane ^ ((nl & 7) << 2);
        Arow[0 + lx]   = a0;
        Arow[64 + lx]  = a1;
        Arow[128 + lx] = a2;
        Arow[192 + lx] = a3;
        Arow[256 + lx] = self;
    }
    __syncthreads();

    // phase 2: C[32n x 64h] = A[32 x 320] * Wc[320 x 64]; 2 nodes x 4 h per thread
    const int n0 = (tid & 15) << 1;
    const int h0 = (tid >> 4) << 2;
    const int ca = (n0 & 7) << 2;
    const int cb = ((n0 + 1) & 7) << 2;
    const float* Arow0 = &A2[n0 * KDIM];
    const float* Arow1 = &A2[(n0 + 1) * KDIM];

    float cc[2][4];
#pragma unroll
    for (int i = 0; i < 2; ++i)
#pragma unroll
        for (int j = 0; j < 4; ++j) cc[i][j] = 0.f;

#pragma unroll 4
    for (int k0 = 0; k0 < KDIM; k0 += 4) {
        const float4 a0 = *reinterpret_cast<const float4*>(&Arow0[k0 ^ ca]);
        const float4 a1 = *reinterpret_cast<const float4*>(&Arow1[k0 ^ cb]);
        const float4 w0 = *reinterpret_cast<const float4*>(&Wc[(k0 + 0) * 64 + h0]);
        const float4 w1 = *reinterpret_cast<const float4*>(&Wc[(k0 + 1) * 64 + h0]);
        const float4 w2 = *reinterpret_cast<const float4*>(&Wc[(k0 + 2) * 64 + h0]);
        const float4 w3 = *reinterpret_cast<const float4*>(&Wc[(k0 + 3) * 64 + h0]);
        cc[0][0] += a0.x * w0.x; cc[0][1] += a0.x * w0.y; cc[0][2] += a0.x * w0.z; cc[0][3] += a0.x * w0.w;
        cc[0][0] += a0.y * w1.x; cc[0][1] += a0.y * w1.y; cc[0][2] += a0.y * w1.z; cc[0][3] += a0.y * w1.w;
        cc[0][0] += a0.z * w2.x; cc[0][1] += a0.z * w2.y; cc[0][2] += a0.z * w2.z; cc[0][3] += a0.z * w2.w;
        cc[0][0] += a0.w * w3.x; cc[0][1] += a0.w * w3.y; cc[0][2] += a0.w * w3.z; cc[0][3] += a0.w * w3.w;
        cc[1][0] += a1.x * w0.x; cc[1][1] += a1.x * w0.y; cc[1][2] += a1.x * w0.z; cc[1][3] += a1.x * w0.w;
        cc[1][0] += a1.y * w1.x; cc[1][1] += a1.y * w1.y; cc[1][2] += a1.y * w1.z; cc[1][3] += a1.y * w1.w;
        cc[1][0] += a1.z * w2.x; cc[1][1] += a1.z * w2.y; cc[1][2] += a1.z * w2.z; cc[1][3] += a1.z * w2.w;
        cc[1][0] += a1.w * w3.x; cc[1][1] += a1.w * w3.y; cc[1][2] += a1.w * w3.z; cc[1][3] += a1.w * w3.w;
    }

    const float b0 = bias[h0 + 0], b1 = bias[h0 + 1], b2 = bias[h0 + 2], b3 = bias[h0 + 3];
#pragma unroll
    for (int i = 0; i < 2; ++i) {
        int n = tile + n0 + i;
        if (n < nN) {
            float4 o;
            o.x = fmaxf(cc[i][0] + b0, 0.f);
            o.y = fmaxf(cc[i][1] + b1, 0.f);
            o.z = fmaxf(cc[i][2] + b2, 0.f);
            o.w = fmaxf(cc[i][3] + b3, 0.f);
            *reinterpret_cast<float4*>(&hout[(size_t)n * 64 + h0]) = o;
        }
    }
}

// ---------------- pooling ----------------

__global__ void k_pool(const float* __restrict__ h, const int* __restrict__ batch,
                       float* __restrict__ g_sum, int nN) {
    int gid = blockIdx.x * 256 + threadIdx.x;
    int hi = gid & 63;
    int n0 = (gid >> 6) * 8;
    if (n0 >= nN) return;
    int end = n0 + 8;
    if (end > nN) end = nN;
    float acc = 0.f;
    int cur = batch[n0];
    for (int n = n0; n < end; ++n) {
        int b = batch[n];
        if (b != cur) {
            atomicAdd(&g_sum[cur * 64 + hi], acc);
            acc = 0.f;
            cur = b;
        }
        acc += h[(size_t)n * 64 + hi];
    }
    atomicAdd(&g_sum[cur * 64 + hi], acc);
}

__global__ void k_cntg(const int* __restrict__ batch, float* __restrict__ cnt_g, int nN) {
    int n = blockIdx.x * 256 + threadIdx.x;
    if (n < nN) atomicAdd(&cnt_g[batch[n]], 1.0f);
}

// ---------------- final MLP: g -> relu(g@w1+b1) -> @w2+b2 ----------------

__global__ void k_mlp(const float* __restrict__ g_sum, const float* __restrict__ cnt_g,
                      const float* __restrict__ w1, const float* __restrict__ b1,
                      const float* __restrict__ w2, const float* __restrict__ b2,
                      float* __restrict__ out) {
    __shared__ float sg[64];
    __shared__ float sh[64];
    int g = blockIdx.x;
    int h = threadIdx.x;
    float c = cnt_g[g];
    sg[h] = g_sum[g * 64 + h] / fmaxf(c, 1.0f);
    __syncthreads();
    float acc = b1[h];
#pragma unroll
    for (int f = 0; f < 64; ++f) acc += sg[f] * w1[f * 64 + h];
    sh[h] = fmaxf(acc, 0.f);
    __syncthreads();
    if (h < 10) {
        float o = b2[h];
#pragma unroll
        for (int f = 0; f < 64; ++f) o += sh[f] * w2[f * 10 + h];
        out[g * 10 + h] = o;
    }
}

// ---------------- launch ----------------

extern "C" void kernel_launch(void* const* d_in, const int* in_sizes, int n_in,
                              void* d_out, int out_size, void* d_ws, size_t ws_size,
                              hipStream_t stream) {
    const float* x     = (const float*)d_in[0];
    const int*   ei    = (const int*)d_in[1];
    const int*   et    = (const int*)d_in[2];
    const int*   batch = (const int*)d_in[3];
    const float* W1    = (const float*)d_in[4];
    const float* root1 = (const float*)d_in[5];
    const float* b1    = (const float*)d_in[6];
    const float* Wl    = (const float*)d_in[7];
    const float* rootl = (const float*)d_in[8];
    const float* bl    = (const float*)d_in[9];
    const float* l1w   = (const float*)d_in[10];
    const float* l1b   = (const float*)d_in[11];
    const float* l2w   = (const float*)d_in[12];
    const float* l2b   = (const float*)d_in[13];
    float* out = (float*)d_out;

    const int N = in_sizes[3];
    const int E = in_sizes[2];
    const int G = out_size / 10;
    const int M = 4 * N;

    const int* src = ei;
    const int* dst = ei + E;

    // workspace carve-out (512B aligned)
    char* base = (char*)d_ws;
    size_t off = 0;
    auto carve = [&](size_t bytes) {
        char* p = base + off;
        off = (off + bytes + 511) & ~(size_t)511;
        return p;
    };
    int*   cnt4    = (int*)carve((size_t)M * 4);
    int*   start4  = (int*)carve((size_t)(M + 1) * 4);
    int*   cursor4 = (int*)carve((size_t)M * 4);
    int*   elist   = (int*)carve((size_t)E * 4);
    int*   bsum    = (int*)carve(512 * 4);
    int*   boff    = (int*)carve(512 * 4);
    float* Wcat    = (float*)carve((size_t)3 * 320 * 64 * 4);
    float* h_a     = (float*)carve((size_t)N * 64 * 4);
    float* h_b     = (float*)carve((size_t)N * 64 * 4);
    float* g_sum   = (float*)carve((size_t)G * 64 * 4);
    float* cnt_g   = (float*)carve((size_t)G * 4);
    (void)ws_size;

    hipMemsetAsync(cnt4, 0, (size_t)M * 4, stream);
    hipMemsetAsync(cursor4, 0, (size_t)M * 4, stream);
    hipMemsetAsync(g_sum, 0, (size_t)G * 64 * 4, stream);
    hipMemsetAsync(cnt_g, 0, (size_t)G * 4, stream);

    k_count<<<(E + 255) / 256, 256, 0, stream>>>(dst, et, cnt4, E);

    int nb = (M + 1023) / 1024;
    k_scan1<<<nb, 256, 0, stream>>>(cnt4, start4, bsum, M);
    k_scan2<<<1, 512, 0, stream>>>(bsum, boff, nb);
    k_scan3<<<(M + 1 + 255) / 256, 256, 0, stream>>>(start4, boff, M, E);
    k_fill<<<(E + 255) / 256, 256, 0, stream>>>(src, dst, et, start4, cursor4, elist, E);

    k_wcat<<<(3 * 320 * 64 + 255) / 256, 256, 0, stream>>>(W1, root1, Wl, rootl, Wcat);

    const int cb = (N + TILE - 1) / TILE;
    k_conv<<<cb, 256, 0, stream>>>(x,   h_a, elist, start4, Wcat,                b1,      N);
    k_conv<<<cb, 256, 0, stream>>>(h_a, h_b, elist, start4, Wcat + 320 * 64,     bl,      N);
    k_conv<<<cb, 256, 0, stream>>>(h_b, h_a, elist, start4, Wcat + 2 * 320 * 64, bl + 64, N);

    k_pool<<<(((N + 7) / 8) * 64 + 255) / 256, 256, 0, stream>>>(h_a, batch, g_sum, N);
    k_cntg<<<(N + 255) / 256, 256, 0, stream>>>(batch, cnt_g, N);
    k_mlp<<<G, 64, 0, stream>>>(g_sum, cnt_g, l1w, l1b, l2w, l2b, out);
}

// Round 6
// 537.367 us; speedup vs baseline: 4.3030x; 1.5545x over previous
//
#include <hip/hip_runtime.h>

#define TILE 32
#define KDIM 320

typedef __attribute__((ext_vector_type(8))) short short8;
typedef __attribute__((ext_vector_type(4))) float f32x4;

__device__ inline unsigned short rne_bf16(float f) {
    union { float f; unsigned u; } x;
    x.f = f;
    unsigned r = (x.u + 0x7FFF + ((x.u >> 16) & 1)) >> 16;
    return (unsigned short)r;
}

// ---------------- CSR build ----------------

__global__ void k_count(const int* __restrict__ dst, const int* __restrict__ typ,
                        int* __restrict__ cnt4, int E) {
    int e = blockIdx.x * 256 + threadIdx.x;
    if (e < E) atomicAdd(&cnt4[dst[e] * 4 + typ[e]], 1);
}

// exclusive scan over M=4N elems; 1024 elems/block
__global__ void k_scan1(const int* __restrict__ in, int* __restrict__ out,
                        int* __restrict__ bsum, int M) {
    __shared__ int s[256];
    int t = threadIdx.x;
    int base = blockIdx.x * 1024 + t * 4;
    int v0 = (base + 0 < M) ? in[base + 0] : 0;
    int v1 = (base + 1 < M) ? in[base + 1] : 0;
    int v2 = (base + 2 < M) ? in[base + 2] : 0;
    int v3 = (base + 3 < M) ? in[base + 3] : 0;
    int ts = v0 + v1 + v2 + v3;
    s[t] = ts;
    __syncthreads();
    for (int off = 1; off < 256; off <<= 1) {
        int x = (t >= off) ? s[t - off] : 0;
        __syncthreads();
        s[t] += x;
        __syncthreads();
    }
    int excl = (t == 0) ? 0 : s[t - 1];
    if (t == 255) bsum[blockIdx.x] = s[255];
    if (base + 0 < M) out[base + 0] = excl;
    if (base + 1 < M) out[base + 1] = excl + v0;
    if (base + 2 < M) out[base + 2] = excl + v0 + v1;
    if (base + 3 < M) out[base + 3] = excl + v0 + v1 + v2;
}

__global__ void k_scan2(const int* __restrict__ bsum, int* __restrict__ boff, int nb) {
    __shared__ int s[512];
    int t = threadIdx.x;
    s[t] = (t < nb) ? bsum[t] : 0;
    __syncthreads();
    for (int off = 1; off < 512; off <<= 1) {
        int x = (t >= off) ? s[t - off] : 0;
        __syncthreads();
        s[t] += x;
        __syncthreads();
    }
    if (t < nb) boff[t] = (t == 0) ? 0 : s[t - 1];
}

__global__ void k_scan3(int* __restrict__ out, const int* __restrict__ boff, int M, int E) {
    int i = blockIdx.x * 256 + threadIdx.x;
    if (i < M) out[i] += boff[i >> 10];
    else if (i == M) out[M] = E;
}

__global__ void k_fill(const int* __restrict__ src, const int* __restrict__ dst,
                       const int* __restrict__ typ, const int* __restrict__ start4,
                       int* __restrict__ cursor4, int* __restrict__ elist, int E) {
    int e = blockIdx.x * 256 + threadIdx.x;
    if (e < E) {
        int seg = dst[e] * 4 + typ[e];
        int p = atomicAdd(&cursor4[seg], 1);
        elist[start4[seg] + p] = src[e];
    }
}

// ---------------- weight pack: MFMA B-fragment order, bf16 ----------------
// Wp[layer][nt(4)][ks(10)][lane(64)][j(8)] = W[ks*32 + (lane>>4)*8 + j][nt*16 + (lane&15)]
// where W = concat(W_r rows 0..255, root rows 256..319) of that layer.

__global__ void k_wpack(const float* __restrict__ W1, const float* __restrict__ root1,
                        const float* __restrict__ Wl, const float* __restrict__ rootl,
                        unsigned short* __restrict__ Wp) {
    int idx = blockIdx.x * 256 + threadIdx.x;
    const int TOT = 3 * 320 * 64;
    if (idx >= TOT) return;
    int j = idx & 7;
    int lane = (idx >> 3) & 63;
    int t = idx >> 9;          // (layer*4 + nt)*10 + ks
    int ks = t % 10;
    int lnt = t / 10;          // layer*4 + nt
    int nt = lnt & 3;
    int layer = lnt >> 2;
    int k = ks * 32 + ((lane >> 4) << 3) + j;
    int h = nt * 16 + (lane & 15);
    float v;
    if (k < 256) {
        v = (layer == 0) ? W1[k * 64 + h] : Wl[(layer - 1) * 16384 + k * 64 + h];
    } else {
        v = (layer == 0) ? root1[(k - 256) * 64 + h]
                         : rootl[(layer - 1) * 4096 + (k - 256) * 64 + h];
    }
    Wp[idx] = rne_bf16(v);
}

// ---------------- fused RGCN conv layer ----------------
// A-tile in LDS as bf16, MFMA-frag friendly:
//   element (n, k) at ushort offset n*320 + (kc&~7)*8 + (((kc&7)^(n&7))*8) + (k&7),
//   kc = k>>3. 16B-chunk XOR swizzle spreads fragment reads across bank quads.

__global__ __launch_bounds__(256, 6) void k_conv(
        const float* __restrict__ hin, float* __restrict__ hout,
        const int* __restrict__ elist, const int* __restrict__ start4,
        const unsigned short* __restrict__ Wp, const float* __restrict__ bias, int nN) {
    __shared__ unsigned short A2[TILE * KDIM];  // 20 KB
    const int tid = threadIdx.x;
    const int lane = tid & 63;
    const int wv = tid >> 6;
    const int tile = blockIdx.x * TILE;

    // phase 1: each wave aggregates 8 nodes; flat edge loop, unroll x8,
    // suffix-sum relation routing; write bf16 into swizzled A-tile.
    for (int jj = 0; jj < 8; ++jj) {
        int nl = wv * 8 + jj;
        int n = tile + nl;
        unsigned short* Arow = &A2[nl * KDIM];
        const int sw = (((lane >> 3) ^ (nl & 7)) << 3) + (lane & 7);
        if (n >= nN) {
#pragma unroll
            for (int seg = 0; seg < 5; ++seg) Arow[seg * 64 + sw] = 0;
            continue;
        }
        const int* s4 = start4 + n * 4;
        int e0 = s4[0], e1 = s4[1], e2 = s4[2], e3 = s4[3], e4 = s4[4];
        float self = hin[(size_t)n * 64 + lane];
        float S0 = 0.f, S1 = 0.f, S2 = 0.f, S3 = 0.f;
        for (int p = e0; p < e4; p += 8) {
            int qidx[8];
#pragma unroll
            for (int u = 0; u < 8; ++u) {
                int q = p + u;
                qidx[u] = elist[(q < e4) ? q : e0];
            }
            float v[8];
#pragma unroll
            for (int u = 0; u < 8; ++u)
                v[u] = hin[(size_t)qidx[u] * 64 + lane];
#pragma unroll
            for (int u = 0; u < 8; ++u) {
                int q = p + u;
                float t = (q < e4) ? v[u] : 0.f;
                S0 += t;
                S1 += (q >= e1) ? t : 0.f;
                S2 += (q >= e2) ? t : 0.f;
                S3 += (q >= e3) ? t : 0.f;
            }
        }
        int c0 = e1 - e0, c1 = e2 - e1, c2 = e3 - e2, c3 = e4 - e3;
        float a0 = (S0 - S1) * ((c0 > 0) ? 1.0f / (float)c0 : 0.f);
        float a1 = (S1 - S2) * ((c1 > 0) ? 1.0f / (float)c1 : 0.f);
        float a2 = (S2 - S3) * ((c2 > 0) ? 1.0f / (float)c2 : 0.f);
        float a3 = S3 * ((c3 > 0) ? 1.0f / (float)c3 : 0.f);
        Arow[0   + sw] = rne_bf16(a0);
        Arow[64  + sw] = rne_bf16(a1);
        Arow[128 + sw] = rne_bf16(a2);
        Arow[192 + sw] = rne_bf16(a3);
        Arow[256 + sw] = rne_bf16(self);
    }
    __syncthreads();

    // phase 2: C[32 x 64] = A[32 x 320] * W[320 x 64] via mfma_f32_16x16x32_bf16.
    // wave wv: m-tile = wv&1, n-tiles = {(wv>>1)*2, (wv>>1)*2+1}; A-frag shared.
    const int mt = wv & 1;
    const int ntb = (wv >> 1) << 1;
    const int nloc = mt * 16 + (lane & 15);
    f32x4 acc0 = {0.f, 0.f, 0.f, 0.f};
    f32x4 acc1 = {0.f, 0.f, 0.f, 0.f};
    const unsigned short* wp0 = Wp + ((size_t)(ntb * 10) * 64 + lane) * 8;
    const unsigned short* wp1 = Wp + ((size_t)((ntb + 1) * 10) * 64 + lane) * 8;
#pragma unroll 2
    for (int ks = 0; ks < 10; ++ks) {
        int kc = ks * 4 + (lane >> 4);
        int swz = (kc & ~7) | ((kc & 7) ^ (lane & 7));
        short8 a = *reinterpret_cast<const short8*>(&A2[nloc * KDIM + swz * 8]);
        short8 b0 = *reinterpret_cast<const short8*>(&wp0[ks * 512]);
        short8 b1 = *reinterpret_cast<const short8*>(&wp1[ks * 512]);
        acc0 = __builtin_amdgcn_mfma_f32_16x16x32_bf16(a, b0, acc0, 0, 0, 0);
        acc1 = __builtin_amdgcn_mfma_f32_16x16x32_bf16(a, b1, acc1, 0, 0, 0);
    }
    // C/D: col = lane&15, row = (lane>>4)*4 + reg
    const int h0 = ntb * 16 + (lane & 15);
    const int nr = tile + mt * 16 + ((lane >> 4) << 2);
    const float bb0 = bias[h0];
    const float bb1 = bias[h0 + 16];
#pragma unroll
    for (int r = 0; r < 4; ++r) {
        int n = nr + r;
        if (n < nN) {
            hout[(size_t)n * 64 + h0]      = fmaxf(acc0[r] + bb0, 0.f);
            hout[(size_t)n * 64 + h0 + 16] = fmaxf(acc1[r] + bb1, 0.f);
        }
    }
}

// ---------------- pooling ----------------

__global__ void k_pool(const float* __restrict__ h, const int* __restrict__ batch,
                       float* __restrict__ g_sum, int nN) {
    int gid = blockIdx.x * 256 + threadIdx.x;
    int hi = gid & 63;
    int n0 = (gid >> 6) * 8;
    if (n0 >= nN) return;
    int end = n0 + 8;
    if (end > nN) end = nN;
    float acc = 0.f;
    int cur = batch[n0];
    for (int n = n0; n < end; ++n) {
        int b = batch[n];
        if (b != cur) {
            atomicAdd(&g_sum[cur * 64 + hi], acc);
            acc = 0.f;
            cur = b;
        }
        acc += h[(size_t)n * 64 + hi];
    }
    atomicAdd(&g_sum[cur * 64 + hi], acc);
}

__global__ void k_cntg(const int* __restrict__ batch, float* __restrict__ cnt_g, int nN) {
    int n = blockIdx.x * 256 + threadIdx.x;
    if (n < nN) atomicAdd(&cnt_g[batch[n]], 1.0f);
}

// ---------------- final MLP: g -> relu(g@w1+b1) -> @w2+b2 ----------------

__global__ void k_mlp(const float* __restrict__ g_sum, const float* __restrict__ cnt_g,
                      const float* __restrict__ w1, const float* __restrict__ b1,
                      const float* __restrict__ w2, const float* __restrict__ b2,
                      float* __restrict__ out) {
    __shared__ float sg[64];
    __shared__ float sh[64];
    int g = blockIdx.x;
    int h = threadIdx.x;
    float c = cnt_g[g];
    sg[h] = g_sum[g * 64 + h] / fmaxf(c, 1.0f);
    __syncthreads();
    float acc = b1[h];
#pragma unroll
    for (int f = 0; f < 64; ++f) acc += sg[f] * w1[f * 64 + h];
    sh[h] = fmaxf(acc, 0.f);
    __syncthreads();
    if (h < 10) {
        float o = b2[h];
#pragma unroll
        for (int f = 0; f < 64; ++f) o += sh[f] * w2[f * 10 + h];
        out[g * 10 + h] = o;
    }
}

// ---------------- launch ----------------

extern "C" void kernel_launch(void* const* d_in, const int* in_sizes, int n_in,
                              void* d_out, int out_size, void* d_ws, size_t ws_size,
                              hipStream_t stream) {
    const float* x     = (const float*)d_in[0];
    const int*   ei    = (const int*)d_in[1];
    const int*   et    = (const int*)d_in[2];
    const int*   batch = (const int*)d_in[3];
    const float* W1    = (const float*)d_in[4];
    const float* root1 = (const float*)d_in[5];
    const float* b1    = (const float*)d_in[6];
    const float* Wl    = (const float*)d_in[7];
    const float* rootl = (const float*)d_in[8];
    const float* bl    = (const float*)d_in[9];
    const float* l1w   = (const float*)d_in[10];
    const float* l1b   = (const float*)d_in[11];
    const float* l2w   = (const float*)d_in[12];
    const float* l2b   = (const float*)d_in[13];
    float* out = (float*)d_out;

    const int N = in_sizes[3];
    const int E = in_sizes[2];
    const int G = out_size / 10;
    const int M = 4 * N;

    const int* src = ei;
    const int* dst = ei + E;

    // workspace carve-out (512B aligned)
    char* base = (char*)d_ws;
    size_t off = 0;
    auto carve = [&](size_t bytes) {
        char* p = base + off;
        off = (off + bytes + 511) & ~(size_t)511;
        return p;
    };
    int*   cnt4    = (int*)carve((size_t)M * 4);
    int*   start4  = (int*)carve((size_t)(M + 1) * 4);
    int*   cursor4 = (int*)carve((size_t)M * 4);
    int*   elist   = (int*)carve((size_t)E * 4);
    int*   bsum    = (int*)carve(512 * 4);
    int*   boff    = (int*)carve(512 * 4);
    unsigned short* Wpack = (unsigned short*)carve((size_t)3 * 320 * 64 * 2);
    float* h_a     = (float*)carve((size_t)N * 64 * 4);
    float* h_b     = (float*)carve((size_t)N * 64 * 4);
    float* g_sum   = (float*)carve((size_t)G * 64 * 4);
    float* cnt_g   = (float*)carve((size_t)G * 4);
    (void)ws_size;

    hipMemsetAsync(cnt4, 0, (size_t)M * 4, stream);
    hipMemsetAsync(cursor4, 0, (size_t)M * 4, stream);
    hipMemsetAsync(g_sum, 0, (size_t)G * 64 * 4, stream);
    hipMemsetAsync(cnt_g, 0, (size_t)G * 4, stream);

    k_count<<<(E + 255) / 256, 256, 0, stream>>>(dst, et, cnt4, E);

    int nb = (M + 1023) / 1024;
    k_scan1<<<nb, 256, 0, stream>>>(cnt4, start4, bsum, M);
    k_scan2<<<1, 512, 0, stream>>>(bsum, boff, nb);
    k_scan3<<<(M + 1 + 255) / 256, 256, 0, stream>>>(start4, boff, M, E);
    k_fill<<<(E + 255) / 256, 256, 0, stream>>>(src, dst, et, start4, cursor4, elist, E);

    k_wpack<<<(3 * 320 * 64 + 255) / 256, 256, 0, stream>>>(W1, root1, Wl, rootl, Wpack);

    const int cb = (N + TILE - 1) / TILE;
    const int WSTRIDE = 320 * 64;  // ushorts per layer
    k_conv<<<cb, 256, 0, stream>>>(x,   h_a, elist, start4, Wpack,               b1,      N);
    k_conv<<<cb, 256, 0, stream>>>(h_a, h_b, elist, start4, Wpack + WSTRIDE,     bl,      N);
    k_conv<<<cb, 256, 0, stream>>>(h_b, h_a, elist, start4, Wpack + 2 * WSTRIDE, bl + 64, N);

    k_pool<<<(((N + 7) / 8) * 64 + 255) / 256, 256, 0, stream>>>(h_a, batch, g_sum, N);
    k_cntg<<<(N + 255) / 256, 256, 0, stream>>>(batch, cnt_g, N);
    k_mlp<<<G, 64, 0, stream>>>(g_sum, cnt_g, l1w, l1b, l2w, l2b, out);
}

// Round 7
// 450.989 us; speedup vs baseline: 5.1271x; 1.1915x over previous
//
#include <hip/hip_runtime.h>

#define TILE 32
#define KDIM 320

typedef __attribute__((ext_vector_type(8))) short short8;
typedef __attribute__((ext_vector_type(4))) float f32x4;

__device__ inline unsigned short rne_bf16(float f) {
    union { float f; unsigned u; } x;
    x.f = f;
    unsigned r = (x.u + 0x7FFF + ((x.u >> 16) & 1)) >> 16;
    return (unsigned short)r;
}

__device__ inline float bf16_f(unsigned short v) {
    union { unsigned u; float f; } x;
    x.u = ((unsigned)v) << 16;
    return x.f;
}

// ---------------- CSR build ----------------

__global__ void k_count(const int* __restrict__ dst, const int* __restrict__ typ,
                        int* __restrict__ cnt4, int E) {
    int e = blockIdx.x * 256 + threadIdx.x;
    if (e < E) atomicAdd(&cnt4[dst[e] * 4 + typ[e]], 1);
}

__global__ void k_scan1(const int* __restrict__ in, int* __restrict__ out,
                        int* __restrict__ bsum, int M) {
    __shared__ int s[256];
    int t = threadIdx.x;
    int base = blockIdx.x * 1024 + t * 4;
    int v0 = (base + 0 < M) ? in[base + 0] : 0;
    int v1 = (base + 1 < M) ? in[base + 1] : 0;
    int v2 = (base + 2 < M) ? in[base + 2] : 0;
    int v3 = (base + 3 < M) ? in[base + 3] : 0;
    int ts = v0 + v1 + v2 + v3;
    s[t] = ts;
    __syncthreads();
    for (int off = 1; off < 256; off <<= 1) {
        int x = (t >= off) ? s[t - off] : 0;
        __syncthreads();
        s[t] += x;
        __syncthreads();
    }
    int excl = (t == 0) ? 0 : s[t - 1];
    if (t == 255) bsum[blockIdx.x] = s[255];
    if (base + 0 < M) out[base + 0] = excl;
    if (base + 1 < M) out[base + 1] = excl + v0;
    if (base + 2 < M) out[base + 2] = excl + v0 + v1;
    if (base + 3 < M) out[base + 3] = excl + v0 + v1 + v2;
}

__global__ void k_scan2(const int* __restrict__ bsum, int* __restrict__ boff, int nb) {
    __shared__ int s[512];
    int t = threadIdx.x;
    s[t] = (t < nb) ? bsum[t] : 0;
    __syncthreads();
    for (int off = 1; off < 512; off <<= 1) {
        int x = (t >= off) ? s[t - off] : 0;
        __syncthreads();
        s[t] += x;
        __syncthreads();
    }
    if (t < nb) boff[t] = (t == 0) ? 0 : s[t - 1];
}

__global__ void k_scan3(int* __restrict__ out, const int* __restrict__ boff, int M, int E) {
    int i = blockIdx.x * 256 + threadIdx.x;
    if (i < M) out[i] += boff[i >> 10];
    else if (i == M) out[M] = E;
}

__global__ void k_fill(const int* __restrict__ src, const int* __restrict__ dst,
                       const int* __restrict__ typ, const int* __restrict__ start4,
                       int* __restrict__ cursor4, int* __restrict__ elist, int E) {
    int e = blockIdx.x * 256 + threadIdx.x;
    if (e < E) {
        int seg = dst[e] * 4 + typ[e];
        int p = atomicAdd(&cursor4[seg], 1);
        elist[start4[seg] + p] = src[e];
    }
}

// ---------------- x -> bf16 ----------------

__global__ void k_cvt(const float* __restrict__ x, unsigned short* __restrict__ xb, int total) {
    int i = (blockIdx.x * 256 + threadIdx.x) * 4;
    if (i + 3 < total) {
        float4 v = *reinterpret_cast<const float4*>(&x[i]);
        ushort4 o;
        o.x = rne_bf16(v.x); o.y = rne_bf16(v.y);
        o.z = rne_bf16(v.z); o.w = rne_bf16(v.w);
        *reinterpret_cast<ushort4*>(&xb[i]) = o;
    } else {
        for (int j = i; j < total; ++j) xb[j] = rne_bf16(x[j]);
    }
}

// ---------------- graph boundaries (sorted batch, no atomics) ----------------
// gstart[g] = first node index n with batch[n] >= g; gstart[G] = N.

__global__ void k_gbound(const int* __restrict__ batch, int* __restrict__ gstart,
                         int nN, int nG) {
    int n = blockIdx.x * 256 + threadIdx.x;
    if (n >= nN) return;
    int b = batch[n];
    if (n == 0) {
        for (int g = 0; g <= b; ++g) gstart[g] = 0;
    } else {
        int bp = batch[n - 1];
        for (int g = bp + 1; g <= b; ++g) gstart[g] = n;
    }
    if (n == nN - 1) {
        for (int g = b + 1; g <= nG; ++g) gstart[g] = nN;
    }
}

// ---------------- weight pack: MFMA B-fragment order, bf16 ----------------
// Wp[layer][nt(4)][ks(10)][lane(64)][j(8)] = W[ks*32 + (lane>>4)*8 + j][nt*16 + (lane&15)]

__global__ void k_wpack(const float* __restrict__ W1, const float* __restrict__ root1,
                        const float* __restrict__ Wl, const float* __restrict__ rootl,
                        unsigned short* __restrict__ Wp) {
    int idx = blockIdx.x * 256 + threadIdx.x;
    const int TOT = 3 * 320 * 64;
    if (idx >= TOT) return;
    int j = idx & 7;
    int lane = (idx >> 3) & 63;
    int t = idx >> 9;
    int ks = t % 10;
    int lnt = t / 10;
    int nt = lnt & 3;
    int layer = lnt >> 2;
    int k = ks * 32 + ((lane >> 4) << 3) + j;
    int h = nt * 16 + (lane & 15);
    float v;
    if (k < 256) {
        v = (layer == 0) ? W1[k * 64 + h] : Wl[(layer - 1) * 16384 + k * 64 + h];
    } else {
        v = (layer == 0) ? root1[(k - 256) * 64 + h]
                         : rootl[(layer - 1) * 4096 + (k - 256) * 64 + h];
    }
    Wp[idx] = rne_bf16(v);
}

// ---------------- fused RGCN conv layer (bf16 in / bf16 out) ----------------
// A-tile LDS layout: element (n, k) at n*320 + (kc&~7)*8 + (((kc>>0&7)^(n&7))*8) + (k&7)

__global__ __launch_bounds__(256, 6) void k_conv(
        const unsigned short* __restrict__ hin, unsigned short* __restrict__ hout,
        const int* __restrict__ elist, const int* __restrict__ start4,
        const unsigned short* __restrict__ Wp, const float* __restrict__ bias, int nN) {
    __shared__ unsigned short A2[TILE * KDIM];  // 20 KB
    const int tid = threadIdx.x;
    const int lane = tid & 63;
    const int wv = tid >> 6;
    const int tile = blockIdx.x * TILE;

    // phase 1: each wave aggregates 8 nodes; flat edge loop, unroll x8,
    // suffix-sum relation routing; bf16 gathers, fp32 accumulate.
    for (int jj = 0; jj < 8; ++jj) {
        int nl = wv * 8 + jj;
        int n = tile + nl;
        unsigned short* Arow = &A2[nl * KDIM];
        const int sw = (((lane >> 3) ^ (nl & 7)) << 3) + (lane & 7);
        if (n >= nN) {
#pragma unroll
            for (int seg = 0; seg < 5; ++seg) Arow[seg * 64 + sw] = 0;
            continue;
        }
        const int* s4 = start4 + n * 4;
        int e0 = s4[0], e1 = s4[1], e2 = s4[2], e3 = s4[3], e4 = s4[4];
        unsigned short selfb = hin[(size_t)n * 64 + lane];
        float S0 = 0.f, S1 = 0.f, S2 = 0.f, S3 = 0.f;
        for (int p = e0; p < e4; p += 8) {
            int qidx[8];
#pragma unroll
            for (int u = 0; u < 8; ++u) {
                int q = p + u;
                qidx[u] = elist[(q < e4) ? q : e0];
            }
            unsigned short vb[8];
#pragma unroll
            for (int u = 0; u < 8; ++u)
                vb[u] = hin[(size_t)qidx[u] * 64 + lane];
#pragma unroll
            for (int u = 0; u < 8; ++u) {
                int q = p + u;
                float t = (q < e4) ? bf16_f(vb[u]) : 0.f;
                S0 += t;
                S1 += (q >= e1) ? t : 0.f;
                S2 += (q >= e2) ? t : 0.f;
                S3 += (q >= e3) ? t : 0.f;
            }
        }
        int c0 = e1 - e0, c1 = e2 - e1, c2 = e3 - e2, c3 = e4 - e3;
        float a0 = (S0 - S1) * ((c0 > 0) ? 1.0f / (float)c0 : 0.f);
        float a1 = (S1 - S2) * ((c1 > 0) ? 1.0f / (float)c1 : 0.f);
        float a2 = (S2 - S3) * ((c2 > 0) ? 1.0f / (float)c2 : 0.f);
        float a3 = S3 * ((c3 > 0) ? 1.0f / (float)c3 : 0.f);
        Arow[0   + sw] = rne_bf16(a0);
        Arow[64  + sw] = rne_bf16(a1);
        Arow[128 + sw] = rne_bf16(a2);
        Arow[192 + sw] = rne_bf16(a3);
        Arow[256 + sw] = selfb;
    }
    __syncthreads();

    // phase 2: C[32 x 64] = A[32 x 320] * W[320 x 64] via mfma_f32_16x16x32_bf16.
    const int mt = wv & 1;
    const int ntb = (wv >> 1) << 1;
    const int nloc = mt * 16 + (lane & 15);
    f32x4 acc0 = {0.f, 0.f, 0.f, 0.f};
    f32x4 acc1 = {0.f, 0.f, 0.f, 0.f};
    const unsigned short* wp0 = Wp + ((size_t)(ntb * 10) * 64 + lane) * 8;
    const unsigned short* wp1 = Wp + ((size_t)((ntb + 1) * 10) * 64 + lane) * 8;
#pragma unroll 2
    for (int ks = 0; ks < 10; ++ks) {
        int kc = ks * 4 + (lane >> 4);
        int swz = (kc & ~7) | ((kc & 7) ^ (lane & 7));
        short8 a = *reinterpret_cast<const short8*>(&A2[nloc * KDIM + swz * 8]);
        short8 b0 = *reinterpret_cast<const short8*>(&wp0[ks * 512]);
        short8 b1 = *reinterpret_cast<const short8*>(&wp1[ks * 512]);
        acc0 = __builtin_amdgcn_mfma_f32_16x16x32_bf16(a, b0, acc0, 0, 0, 0);
        acc1 = __builtin_amdgcn_mfma_f32_16x16x32_bf16(a, b1, acc1, 0, 0, 0);
    }
    // C/D: col = lane&15, row = (lane>>4)*4 + reg
    const int h0 = ntb * 16 + (lane & 15);
    const int nr = tile + mt * 16 + ((lane >> 4) << 2);
    const float bb0 = bias[h0];
    const float bb1 = bias[h0 + 16];
#pragma unroll
    for (int r = 0; r < 4; ++r) {
        int n = nr + r;
        if (n < nN) {
            hout[(size_t)n * 64 + h0]      = rne_bf16(fmaxf(acc0[r] + bb0, 0.f));
            hout[(size_t)n * 64 + h0 + 16] = rne_bf16(fmaxf(acc1[r] + bb1, 0.f));
        }
    }
}

// ---------------- fused mean-pool + MLP ----------------

__global__ void k_poolmlp(const unsigned short* __restrict__ h,
                          const int* __restrict__ gstart,
                          const float* __restrict__ w1, const float* __restrict__ b1,
                          const float* __restrict__ w2, const float* __restrict__ b2,
                          float* __restrict__ out) {
    __shared__ float red[4][64];
    __shared__ float sg[64];
    __shared__ float sh[64];
    int g = blockIdx.x;
    int t = threadIdx.x;
    int f = t & 63;
    int sl = t >> 6;
    int s = gstart[g], e = gstart[g + 1];
    float acc = 0.f;
    for (int n = s + sl; n < e; n += 4)
        acc += bf16_f(h[(size_t)n * 64 + f]);
    red[sl][f] = acc;
    __syncthreads();
    if (sl == 0) {
        int c = e - s;
        float m = (red[0][f] + red[1][f] + red[2][f] + red[3][f]) /
                  (float)((c > 0) ? c : 1);
        sg[f] = m;
    }
    __syncthreads();
    if (sl == 0) {
        float a = b1[f];
#pragma unroll 16
        for (int k = 0; k < 64; ++k) a += sg[k] * w1[k * 64 + f];
        sh[f] = fmaxf(a, 0.f);
    }
    __syncthreads();
    if (t < 10) {
        float o = b2[t];
#pragma unroll 16
        for (int k = 0; k < 64; ++k) o += sh[k] * w2[k * 10 + t];
        out[g * 10 + t] = o;
    }
}

// ---------------- launch ----------------

extern "C" void kernel_launch(void* const* d_in, const int* in_sizes, int n_in,
                              void* d_out, int out_size, void* d_ws, size_t ws_size,
                              hipStream_t stream) {
    const float* x     = (const float*)d_in[0];
    const int*   ei    = (const int*)d_in[1];
    const int*   et    = (const int*)d_in[2];
    const int*   batch = (const int*)d_in[3];
    const float* W1    = (const float*)d_in[4];
    const float* root1 = (const float*)d_in[5];
    const float* b1    = (const float*)d_in[6];
    const float* Wl    = (const float*)d_in[7];
    const float* rootl = (const float*)d_in[8];
    const float* bl    = (const float*)d_in[9];
    const float* l1w   = (const float*)d_in[10];
    const float* l1b   = (const float*)d_in[11];
    const float* l2w   = (const float*)d_in[12];
    const float* l2b   = (const float*)d_in[13];
    float* out = (float*)d_out;

    const int N = in_sizes[3];
    const int E = in_sizes[2];
    const int G = out_size / 10;
    const int M = 4 * N;

    const int* src = ei;
    const int* dst = ei + E;

    char* base = (char*)d_ws;
    size_t off = 0;
    auto carve = [&](size_t bytes) {
        char* p = base + off;
        off = (off + bytes + 511) & ~(size_t)511;
        return p;
    };
    int*   cnt4    = (int*)carve((size_t)M * 4);
    int*   start4  = (int*)carve((size_t)(M + 1) * 4);
    int*   cursor4 = (int*)carve((size_t)M * 4);
    int*   elist   = (int*)carve((size_t)E * 4);
    int*   bsum    = (int*)carve(512 * 4);
    int*   boff    = (int*)carve(512 * 4);
    unsigned short* Wpack = (unsigned short*)carve((size_t)3 * 320 * 64 * 2);
    unsigned short* xb    = (unsigned short*)carve((size_t)N * 64 * 2);
    unsigned short* hb_a  = (unsigned short*)carve((size_t)N * 64 * 2);
    unsigned short* hb_b  = (unsigned short*)carve((size_t)N * 64 * 2);
    int*   gstart  = (int*)carve((size_t)(G + 1) * 4);
    (void)ws_size;

    hipMemsetAsync(cnt4, 0, (size_t)M * 4, stream);
    hipMemsetAsync(cursor4, 0, (size_t)M * 4, stream);

    k_count<<<(E + 255) / 256, 256, 0, stream>>>(dst, et, cnt4, E);

    int nb = (M + 1023) / 1024;
    k_scan1<<<nb, 256, 0, stream>>>(cnt4, start4, bsum, M);
    k_scan2<<<1, 512, 0, stream>>>(bsum, boff, nb);
    k_scan3<<<(M + 1 + 255) / 256, 256, 0, stream>>>(start4, boff, M, E);
    k_fill<<<(E + 255) / 256, 256, 0, stream>>>(src, dst, et, start4, cursor4, elist, E);

    k_wpack<<<(3 * 320 * 64 + 255) / 256, 256, 0, stream>>>(W1, root1, Wl, rootl, Wpack);
    k_cvt<<<((N * 64 / 4) + 255) / 256, 256, 0, stream>>>(x, xb, N * 64);
    k_gbound<<<(N + 255) / 256, 256, 0, stream>>>(batch, gstart, N, G);

    const int cb = (N + TILE - 1) / TILE;
    const int WSTRIDE = 320 * 64;
    k_conv<<<cb, 256, 0, stream>>>(xb,   hb_a, elist, start4, Wpack,               b1,      N);
    k_conv<<<cb, 256, 0, stream>>>(hb_a, hb_b, elist, start4, Wpack + WSTRIDE,     bl,      N);
    k_conv<<<cb, 256, 0, stream>>>(hb_b, hb_a, elist, start4, Wpack + 2 * WSTRIDE, bl + 64, N);

    k_poolmlp<<<G, 256, 0, stream>>>(hb_a, gstart, l1w, l1b, l2w, l2b, out);
}

// Round 8
// 375.852 us; speedup vs baseline: 6.1521x; 1.1999x over previous
//
#include <hip/hip_runtime.h>

#define TILE 32
#define KDIM 320

typedef __attribute__((ext_vector_type(8))) short short8;
typedef __attribute__((ext_vector_type(4))) float f32x4;

__device__ inline unsigned short rne_bf16(float f) {
    union { float f; unsigned u; } x;
    x.f = f;
    unsigned r = (x.u + 0x7FFF + ((x.u >> 16) & 1)) >> 16;
    return (unsigned short)r;
}

__device__ inline float bf16_f(unsigned short v) {
    union { unsigned u; float f; } x;
    x.u = ((unsigned)v) << 16;
    return x.f;
}

// ---------------- CSR build ----------------

__global__ void k_count(const int* __restrict__ dst, const int* __restrict__ typ,
                        int* __restrict__ cnt4, int E) {
    int e = blockIdx.x * 256 + threadIdx.x;
    if (e < E) atomicAdd(&cnt4[dst[e] * 4 + typ[e]], 1);
}

__global__ void k_scan1(const int* __restrict__ in, int* __restrict__ out,
                        int* __restrict__ bsum, int M) {
    __shared__ int s[256];
    int t = threadIdx.x;
    int base = blockIdx.x * 1024 + t * 4;
    int v0 = (base + 0 < M) ? in[base + 0] : 0;
    int v1 = (base + 1 < M) ? in[base + 1] : 0;
    int v2 = (base + 2 < M) ? in[base + 2] : 0;
    int v3 = (base + 3 < M) ? in[base + 3] : 0;
    int ts = v0 + v1 + v2 + v3;
    s[t] = ts;
    __syncthreads();
    for (int off = 1; off < 256; off <<= 1) {
        int x = (t >= off) ? s[t - off] : 0;
        __syncthreads();
        s[t] += x;
        __syncthreads();
    }
    int excl = (t == 0) ? 0 : s[t - 1];
    if (t == 255) bsum[blockIdx.x] = s[255];
    if (base + 0 < M) out[base + 0] = excl;
    if (base + 1 < M) out[base + 1] = excl + v0;
    if (base + 2 < M) out[base + 2] = excl + v0 + v1;
    if (base + 3 < M) out[base + 3] = excl + v0 + v1 + v2;
}

__global__ void k_scan2(const int* __restrict__ bsum, int* __restrict__ boff, int nb) {
    __shared__ int s[512];
    int t = threadIdx.x;
    s[t] = (t < nb) ? bsum[t] : 0;
    __syncthreads();
    for (int off = 1; off < 512; off <<= 1) {
        int x = (t >= off) ? s[t - off] : 0;
        __syncthreads();
        s[t] += x;
        __syncthreads();
    }
    if (t < nb) boff[t] = (t == 0) ? 0 : s[t - 1];
}

__global__ void k_scan3(int* __restrict__ out, const int* __restrict__ boff, int M, int E) {
    int i = blockIdx.x * 256 + threadIdx.x;
    if (i < M) out[i] += boff[i >> 10];
    else if (i == M) out[M] = E;
}

__global__ void k_fill(const int* __restrict__ src, const int* __restrict__ dst,
                       const int* __restrict__ typ, const int* __restrict__ start4,
                       int* __restrict__ cursor4, int* __restrict__ elist, int E) {
    int e = blockIdx.x * 256 + threadIdx.x;
    if (e < E) {
        int seg = dst[e] * 4 + typ[e];
        int p = atomicAdd(&cursor4[seg], 1);
        elist[start4[seg] + p] = src[e];
    }
}

// ---------------- x -> bf16 ----------------

__global__ void k_cvt(const float* __restrict__ x, unsigned short* __restrict__ xb, int total) {
    int i = (blockIdx.x * 256 + threadIdx.x) * 4;
    if (i + 3 < total) {
        float4 v = *reinterpret_cast<const float4*>(&x[i]);
        ushort4 o;
        o.x = rne_bf16(v.x); o.y = rne_bf16(v.y);
        o.z = rne_bf16(v.z); o.w = rne_bf16(v.w);
        *reinterpret_cast<ushort4*>(&xb[i]) = o;
    } else {
        for (int j = i; j < total; ++j) xb[j] = rne_bf16(x[j]);
    }
}

// ---------------- graph boundaries (sorted batch, no atomics) ----------------

__global__ void k_gbound(const int* __restrict__ batch, int* __restrict__ gstart,
                         int nN, int nG) {
    int n = blockIdx.x * 256 + threadIdx.x;
    if (n >= nN) return;
    int b = batch[n];
    if (n == 0) {
        for (int g = 0; g <= b; ++g) gstart[g] = 0;
    } else {
        int bp = batch[n - 1];
        for (int g = bp + 1; g <= b; ++g) gstart[g] = n;
    }
    if (n == nN - 1) {
        for (int g = b + 1; g <= nG; ++g) gstart[g] = nN;
    }
}

// ---------------- weight pack: MFMA B-fragment order, bf16 ----------------

__global__ void k_wpack(const float* __restrict__ W1, const float* __restrict__ root1,
                        const float* __restrict__ Wl, const float* __restrict__ rootl,
                        unsigned short* __restrict__ Wp) {
    int idx = blockIdx.x * 256 + threadIdx.x;
    const int TOT = 3 * 320 * 64;
    if (idx >= TOT) return;
    int j = idx & 7;
    int lane = (idx >> 3) & 63;
    int t = idx >> 9;
    int ks = t % 10;
    int lnt = t / 10;
    int nt = lnt & 3;
    int layer = lnt >> 2;
    int k = ks * 32 + ((lane >> 4) << 3) + j;
    int h = nt * 16 + (lane & 15);
    float v;
    if (k < 256) {
        v = (layer == 0) ? W1[k * 64 + h] : Wl[(layer - 1) * 16384 + k * 64 + h];
    } else {
        v = (layer == 0) ? root1[(k - 256) * 64 + h]
                         : rootl[(layer - 1) * 4096 + (k - 256) * 64 + h];
    }
    Wp[idx] = rne_bf16(v);
}

// ---------------- fused RGCN conv layer (bf16 in / bf16 out) ----------------
// Phase 1: wave-uniform CSR state in SGPRs (readfirstlane) -> elist via SMEM,
// 16-deep gather batches pinned by sched_barrier(0) for MLP.
// A-tile LDS layout: (n, k) at n*320 + (kc&~7)*8 + (((kc&7)^(n&7))*8) + (k&7).

__global__ __launch_bounds__(256, 6) void k_conv(
        const unsigned short* __restrict__ hin, unsigned short* __restrict__ hout,
        const int* __restrict__ elist, const int* __restrict__ start4,
        const unsigned short* __restrict__ Wp, const float* __restrict__ bias, int nN) {
    __shared__ unsigned short A2[TILE * KDIM];  // 20 KB
    const int tid = threadIdx.x;
    const int lane = tid & 63;
    const int wvs = __builtin_amdgcn_readfirstlane(tid >> 6);  // scalar wave id
    const int wv = tid >> 6;
    const int tile = blockIdx.x * TILE;

    for (int jj = 0; jj < 8; ++jj) {
        const int nl = wvs * 8 + jj;     // scalar
        const int n = tile + nl;         // scalar
        unsigned short* Arow = &A2[nl * KDIM];
        const int sw = (((lane >> 3) ^ (nl & 7)) << 3) + (lane & 7);
        if (n >= nN) {
#pragma unroll
            for (int seg = 0; seg < 5; ++seg) Arow[seg * 64 + sw] = 0;
            continue;
        }
        const int e0 = __builtin_amdgcn_readfirstlane(start4[n * 4 + 0]);
        const int e1 = __builtin_amdgcn_readfirstlane(start4[n * 4 + 1]);
        const int e2 = __builtin_amdgcn_readfirstlane(start4[n * 4 + 2]);
        const int e3 = __builtin_amdgcn_readfirstlane(start4[n * 4 + 3]);
        const int e4 = __builtin_amdgcn_readfirstlane(start4[n * 4 + 4]);

        unsigned short selfb = hin[((size_t)n << 6) + lane];
        float S0 = 0.f, S1 = 0.f, S2 = 0.f, S3 = 0.f;
        int p = e0;

        // main: 16-edge groups, scalar edge indices, batched gathers
        for (; p + 16 <= e4; p += 16) {
            int qidx[16];
#pragma unroll
            for (int u = 0; u < 16; ++u)
                qidx[u] = __builtin_amdgcn_readfirstlane(elist[p + u]);
            unsigned short vb[16];
#pragma unroll
            for (int u = 0; u < 16; ++u)
                vb[u] = hin[((size_t)qidx[u] << 6) + lane];
            __builtin_amdgcn_sched_barrier(0);
#pragma unroll
            for (int u = 0; u < 16; ++u) {
                float t = bf16_f(vb[u]);
                int q = p + u;
                S0 += t;
                S1 += (q >= e1) ? t : 0.f;
                S2 += (q >= e2) ? t : 0.f;
                S3 += (q >= e3) ? t : 0.f;
            }
        }
        // tail: 4-edge groups
        for (; p + 4 <= e4; p += 4) {
            int qidx[4];
#pragma unroll
            for (int u = 0; u < 4; ++u)
                qidx[u] = __builtin_amdgcn_readfirstlane(elist[p + u]);
            unsigned short vb[4];
#pragma unroll
            for (int u = 0; u < 4; ++u)
                vb[u] = hin[((size_t)qidx[u] << 6) + lane];
            __builtin_amdgcn_sched_barrier(0);
#pragma unroll
            for (int u = 0; u < 4; ++u) {
                float t = bf16_f(vb[u]);
                int q = p + u;
                S0 += t;
                S1 += (q >= e1) ? t : 0.f;
                S2 += (q >= e2) ? t : 0.f;
                S3 += (q >= e3) ? t : 0.f;
            }
        }
        // tail: scalar
        for (; p < e4; ++p) {
            int qi = __builtin_amdgcn_readfirstlane(elist[p]);
            float t = bf16_f(hin[((size_t)qi << 6) + lane]);
            S0 += t;
            S1 += (p >= e1) ? t : 0.f;
            S2 += (p >= e2) ? t : 0.f;
            S3 += (p >= e3) ? t : 0.f;
        }

        int c0 = e1 - e0, c1 = e2 - e1, c2 = e3 - e2, c3 = e4 - e3;
        float a0 = (S0 - S1) * ((c0 > 0) ? 1.0f / (float)c0 : 0.f);
        float a1 = (S1 - S2) * ((c1 > 0) ? 1.0f / (float)c1 : 0.f);
        float a2 = (S2 - S3) * ((c2 > 0) ? 1.0f / (float)c2 : 0.f);
        float a3 = S3 * ((c3 > 0) ? 1.0f / (float)c3 : 0.f);
        Arow[0   + sw] = rne_bf16(a0);
        Arow[64  + sw] = rne_bf16(a1);
        Arow[128 + sw] = rne_bf16(a2);
        Arow[192 + sw] = rne_bf16(a3);
        Arow[256 + sw] = selfb;
    }
    __syncthreads();

    // phase 2: C[32 x 64] = A[32 x 320] * W[320 x 64] via mfma_f32_16x16x32_bf16.
    const int mt = wv & 1;
    const int ntb = (wv >> 1) << 1;
    const int nloc = mt * 16 + (lane & 15);
    f32x4 acc0 = {0.f, 0.f, 0.f, 0.f};
    f32x4 acc1 = {0.f, 0.f, 0.f, 0.f};
    const unsigned short* wp0 = Wp + ((size_t)(ntb * 10) * 64 + lane) * 8;
    const unsigned short* wp1 = Wp + ((size_t)((ntb + 1) * 10) * 64 + lane) * 8;
#pragma unroll 2
    for (int ks = 0; ks < 10; ++ks) {
        int kc = ks * 4 + (lane >> 4);
        int swz = (kc & ~7) | ((kc & 7) ^ (lane & 7));
        short8 a = *reinterpret_cast<const short8*>(&A2[nloc * KDIM + swz * 8]);
        short8 b0 = *reinterpret_cast<const short8*>(&wp0[ks * 512]);
        short8 b1 = *reinterpret_cast<const short8*>(&wp1[ks * 512]);
        acc0 = __builtin_amdgcn_mfma_f32_16x16x32_bf16(a, b0, acc0, 0, 0, 0);
        acc1 = __builtin_amdgcn_mfma_f32_16x16x32_bf16(a, b1, acc1, 0, 0, 0);
    }
    const int h0 = ntb * 16 + (lane & 15);
    const int nr = tile + mt * 16 + ((lane >> 4) << 2);
    const float bb0 = bias[h0];
    const float bb1 = bias[h0 + 16];
#pragma unroll
    for (int r = 0; r < 4; ++r) {
        int n = nr + r;
        if (n < nN) {
            hout[(size_t)n * 64 + h0]      = rne_bf16(fmaxf(acc0[r] + bb0, 0.f));
            hout[(size_t)n * 64 + h0 + 16] = rne_bf16(fmaxf(acc1[r] + bb1, 0.f));
        }
    }
}

// ---------------- fused mean-pool + MLP ----------------

__global__ void k_poolmlp(const unsigned short* __restrict__ h,
                          const int* __restrict__ gstart,
                          const float* __restrict__ w1, const float* __restrict__ b1,
                          const float* __restrict__ w2, const float* __restrict__ b2,
                          float* __restrict__ out) {
    __shared__ float red[4][64];
    __shared__ float sg[64];
    __shared__ float sh[64];
    int g = blockIdx.x;
    int t = threadIdx.x;
    int f = t & 63;
    int sl = t >> 6;
    int s = gstart[g], e = gstart[g + 1];
    float acc = 0.f;
    for (int n = s + sl; n < e; n += 4)
        acc += bf16_f(h[(size_t)n * 64 + f]);
    red[sl][f] = acc;
    __syncthreads();
    if (sl == 0) {
        int c = e - s;
        float m = (red[0][f] + red[1][f] + red[2][f] + red[3][f]) /
                  (float)((c > 0) ? c : 1);
        sg[f] = m;
    }
    __syncthreads();
    if (sl == 0) {
        float a = b1[f];
#pragma unroll 16
        for (int k = 0; k < 64; ++k) a += sg[k] * w1[k * 64 + f];
        sh[f] = fmaxf(a, 0.f);
    }
    __syncthreads();
    if (t < 10) {
        float o = b2[t];
#pragma unroll 16
        for (int k = 0; k < 64; ++k) o += sh[k] * w2[k * 10 + t];
        out[g * 10 + t] = o;
    }
}

// ---------------- launch ----------------

extern "C" void kernel_launch(void* const* d_in, const int* in_sizes, int n_in,
                              void* d_out, int out_size, void* d_ws, size_t ws_size,
                              hipStream_t stream) {
    const float* x     = (const float*)d_in[0];
    const int*   ei    = (const int*)d_in[1];
    const int*   et    = (const int*)d_in[2];
    const int*   batch = (const int*)d_in[3];
    const float* W1    = (const float*)d_in[4];
    const float* root1 = (const float*)d_in[5];
    const float* b1    = (const float*)d_in[6];
    const float* Wl    = (const float*)d_in[7];
    const float* rootl = (const float*)d_in[8];
    const float* bl    = (const float*)d_in[9];
    const float* l1w   = (const float*)d_in[10];
    const float* l1b   = (const float*)d_in[11];
    const float* l2w   = (const float*)d_in[12];
    const float* l2b   = (const float*)d_in[13];
    float* out = (float*)d_out;

    const int N = in_sizes[3];
    const int E = in_sizes[2];
    const int G = out_size / 10;
    const int M = 4 * N;

    const int* src = ei;
    const int* dst = ei + E;

    char* base = (char*)d_ws;
    size_t off = 0;
    auto carve = [&](size_t bytes) {
        char* p = base + off;
        off = (off + bytes + 511) & ~(size_t)511;
        return p;
    };
    int*   cnt4    = (int*)carve((size_t)M * 4);
    int*   start4  = (int*)carve((size_t)(M + 1) * 4);
    int*   cursor4 = (int*)carve((size_t)M * 4);
    int*   elist   = (int*)carve((size_t)E * 4);
    int*   bsum    = (int*)carve(512 * 4);
    int*   boff    = (int*)carve(512 * 4);
    unsigned short* Wpack = (unsigned short*)carve((size_t)3 * 320 * 64 * 2);
    unsigned short* xb    = (unsigned short*)carve((size_t)N * 64 * 2);
    unsigned short* hb_a  = (unsigned short*)carve((size_t)N * 64 * 2);
    unsigned short* hb_b  = (unsigned short*)carve((size_t)N * 64 * 2);
    int*   gstart  = (int*)carve((size_t)(G + 1) * 4);
    (void)ws_size;

    hipMemsetAsync(cnt4, 0, (size_t)M * 4, stream);
    hipMemsetAsync(cursor4, 0, (size_t)M * 4, stream);

    k_count<<<(E + 255) / 256, 256, 0, stream>>>(dst, et, cnt4, E);

    int nb = (M + 1023) / 1024;
    k_scan1<<<nb, 256, 0, stream>>>(cnt4, start4, bsum, M);
    k_scan2<<<1, 512, 0, stream>>>(bsum, boff, nb);
    k_scan3<<<(M + 1 + 255) / 256, 256, 0, stream>>>(start4, boff, M, E);
    k_fill<<<(E + 255) / 256, 256, 0, stream>>>(src, dst, et, start4, cursor4, elist, E);

    k_wpack<<<(3 * 320 * 64 + 255) / 256, 256, 0, stream>>>(W1, root1, Wl, rootl, Wpack);
    k_cvt<<<((N * 64 / 4) + 255) / 256, 256, 0, stream>>>(x, xb, N * 64);
    k_gbound<<<(N + 255) / 256, 256, 0, stream>>>(batch, gstart, N, G);

    const int cb = (N + TILE - 1) / TILE;
    const int WSTRIDE = 320 * 64;
    k_conv<<<cb, 256, 0, stream>>>(xb,   hb_a, elist, start4, Wpack,               b1,      N);
    k_conv<<<cb, 256, 0, stream>>>(hb_a, hb_b, elist, start4, Wpack + WSTRIDE,     bl,      N);
    k_conv<<<cb, 256, 0, stream>>>(hb_b, hb_a, elist, start4, Wpack + 2 * WSTRIDE, bl + 64, N);

    k_poolmlp<<<G, 256, 0, stream>>>(hb_a, gstart, l1w, l1b, l2w, l2b, out);
}

// Round 9
// 344.526 us; speedup vs baseline: 6.7115x; 1.0909x over previous
//
#include <hip/hip_runtime.h>

#define TILE 32
#define KDIM 320

typedef __attribute__((ext_vector_type(8))) short short8;
typedef __attribute__((ext_vector_type(4))) float f32x4;

__device__ inline unsigned short rne_bf16(float f) {
    union { float f; unsigned u; } x;
    x.f = f;
    unsigned r = (x.u + 0x7FFF + ((x.u >> 16) & 1)) >> 16;
    return (unsigned short)r;
}

__device__ inline float bf16_f(unsigned short v) {
    union { unsigned u; float f; } x;
    x.u = ((unsigned)v) << 16;
    return x.f;
}

// ---------------- CSR build ----------------

__global__ void k_count(const int* __restrict__ dst, const int* __restrict__ typ,
                        int* __restrict__ cnt4, int* __restrict__ rank, int E) {
    int e = blockIdx.x * 256 + threadIdx.x;
    if (e < E) {
        int seg = dst[e] * 4 + typ[e];
        rank[e] = atomicAdd(&cnt4[seg], 1);
    }
}

__global__ void k_scan1(const int* __restrict__ in, int* __restrict__ out,
                        int* __restrict__ bsum, int M) {
    __shared__ int s[256];
    int t = threadIdx.x;
    int base = blockIdx.x * 1024 + t * 4;
    int v0 = (base + 0 < M) ? in[base + 0] : 0;
    int v1 = (base + 1 < M) ? in[base + 1] : 0;
    int v2 = (base + 2 < M) ? in[base + 2] : 0;
    int v3 = (base + 3 < M) ? in[base + 3] : 0;
    int ts = v0 + v1 + v2 + v3;
    s[t] = ts;
    __syncthreads();
    for (int off = 1; off < 256; off <<= 1) {
        int x = (t >= off) ? s[t - off] : 0;
        __syncthreads();
        s[t] += x;
        __syncthreads();
    }
    int excl = (t == 0) ? 0 : s[t - 1];
    if (t == 255) bsum[blockIdx.x] = s[255];
    if (base + 0 < M) out[base + 0] = excl;
    if (base + 1 < M) out[base + 1] = excl + v0;
    if (base + 2 < M) out[base + 2] = excl + v0 + v1;
    if (base + 3 < M) out[base + 3] = excl + v0 + v1 + v2;
}

__global__ void k_scan2(const int* __restrict__ bsum, int* __restrict__ boff, int nb) {
    __shared__ int s[512];
    int t = threadIdx.x;
    s[t] = (t < nb) ? bsum[t] : 0;
    __syncthreads();
    for (int off = 1; off < 512; off <<= 1) {
        int x = (t >= off) ? s[t - off] : 0;
        __syncthreads();
        s[t] += x;
        __syncthreads();
    }
    if (t < nb) boff[t] = (t == 0) ? 0 : s[t - 1];
}

__global__ void k_scan3(int* __restrict__ out, const int* __restrict__ boff, int M, int E) {
    int i = blockIdx.x * 256 + threadIdx.x;
    if (i < M) out[i] += boff[i >> 10];
    else if (i == M) out[M] = E;
}

__global__ void k_fill(const int* __restrict__ src, const int* __restrict__ dst,
                       const int* __restrict__ typ, const int* __restrict__ start4,
                       const int* __restrict__ rank, int* __restrict__ elist, int E) {
    int e = blockIdx.x * 256 + threadIdx.x;
    if (e < E) {
        int seg = dst[e] * 4 + typ[e];
        elist[start4[seg] + rank[e]] = src[e];
    }
}

// ---------------- fused prep: x->bf16 | weight pack | graph bounds ----------------

__global__ void k_prep(const float* __restrict__ x, unsigned short* __restrict__ xb, int ncvt,
                       const float* __restrict__ W1, const float* __restrict__ root1,
                       const float* __restrict__ Wl, const float* __restrict__ rootl,
                       unsigned short* __restrict__ Wp, int nwp,
                       const int* __restrict__ batch, int* __restrict__ gstart,
                       int nN, int nG) {
    int b = blockIdx.x;
    if (b < ncvt) {
        int i = (b * 256 + threadIdx.x) * 4;
        float4 v = *reinterpret_cast<const float4*>(&x[i]);
        ushort4 o;
        o.x = rne_bf16(v.x); o.y = rne_bf16(v.y);
        o.z = rne_bf16(v.z); o.w = rne_bf16(v.w);
        *reinterpret_cast<ushort4*>(&xb[i]) = o;
        return;
    }
    b -= ncvt;
    if (b < nwp) {
        int idx = b * 256 + threadIdx.x;
        const int TOT = 3 * 320 * 64;
        if (idx >= TOT) return;
        int j = idx & 7;
        int lane = (idx >> 3) & 63;
        int t = idx >> 9;
        int ks = t % 10;
        int lnt = t / 10;
        int nt = lnt & 3;
        int layer = lnt >> 2;
        int k = ks * 32 + ((lane >> 4) << 3) + j;
        int h = nt * 16 + (lane & 15);
        float v;
        if (k < 256) {
            v = (layer == 0) ? W1[k * 64 + h] : Wl[(layer - 1) * 16384 + k * 64 + h];
        } else {
            v = (layer == 0) ? root1[(k - 256) * 64 + h]
                             : rootl[(layer - 1) * 4096 + (k - 256) * 64 + h];
        }
        Wp[idx] = rne_bf16(v);
        return;
    }
    b -= nwp;
    {
        int n = b * 256 + threadIdx.x;
        if (n >= nN) return;
        int bb = batch[n];
        if (n == 0) {
            for (int g = 0; g <= bb; ++g) gstart[g] = 0;
        } else {
            int bp = batch[n - 1];
            for (int g = bp + 1; g <= bb; ++g) gstart[g] = n;
        }
        if (n == nN - 1) {
            for (int g = bb + 1; g <= nG; ++g) gstart[g] = nN;
        }
    }
}

// ---------------- fused RGCN conv layer (bf16 in / bf16 out) ----------------
// Phase 1: wave-uniform CSR state in SGPRs; full unclamped 8-groups
// (contiguous scalar elist loads -> SMEM merge) + ONE predicated clamped
// 8-group tail. sched_barrier(0) pins the gather batch before consume.
// A-tile LDS layout: (n, k) at n*320 + (kc&~7)*8 + (((kc&7)^(n&7))*8) + (k&7).

__global__ __launch_bounds__(256, 6) void k_conv(
        const unsigned short* __restrict__ hin, unsigned short* __restrict__ hout,
        const int* __restrict__ elist, const int* __restrict__ start4,
        const unsigned short* __restrict__ Wp, const float* __restrict__ bias, int nN) {
    __shared__ unsigned short A2[TILE * KDIM];  // 20 KB
    const int tid = threadIdx.x;
    const int lane = tid & 63;
    const int wvs = __builtin_amdgcn_readfirstlane(tid >> 6);
    const int wv = tid >> 6;
    const int tile = blockIdx.x * TILE;

    for (int jj = 0; jj < 8; ++jj) {
        const int nl = wvs * 8 + jj;
        const int n = tile + nl;
        unsigned short* Arow = &A2[nl * KDIM];
        const int sw = (((lane >> 3) ^ (nl & 7)) << 3) + (lane & 7);
        if (n >= nN) {
#pragma unroll
            for (int seg = 0; seg < 5; ++seg) Arow[seg * 64 + sw] = 0;
            continue;
        }
        const int e0 = __builtin_amdgcn_readfirstlane(start4[n * 4 + 0]);
        const int e1 = __builtin_amdgcn_readfirstlane(start4[n * 4 + 1]);
        const int e2 = __builtin_amdgcn_readfirstlane(start4[n * 4 + 2]);
        const int e3 = __builtin_amdgcn_readfirstlane(start4[n * 4 + 3]);
        const int e4 = __builtin_amdgcn_readfirstlane(start4[n * 4 + 4]);

        unsigned short selfb = hin[((size_t)n << 6) + lane];
        float S0 = 0.f, S1 = 0.f, S2 = 0.f, S3 = 0.f;
        int p = e0;

        // full groups: no clamps, contiguous scalar elist loads
        for (; p + 8 <= e4; p += 8) {
            int qidx[8];
#pragma unroll
            for (int u = 0; u < 8; ++u)
                qidx[u] = __builtin_amdgcn_readfirstlane(elist[p + u]);
            unsigned short vb[8];
#pragma unroll
            for (int u = 0; u < 8; ++u)
                vb[u] = hin[((size_t)qidx[u] << 6) + lane];
            __builtin_amdgcn_sched_barrier(0);
#pragma unroll
            for (int u = 0; u < 8; ++u) {
                float t = bf16_f(vb[u]);
                int q = p + u;
                S0 += t;
                S1 += (q >= e1) ? t : 0.f;
                S2 += (q >= e2) ? t : 0.f;
                S3 += (q >= e3) ? t : 0.f;
            }
        }
        // one predicated tail group (index clamped, value zero-selected)
        if (p < e4) {
            int qidx[8];
#pragma unroll
            for (int u = 0; u < 8; ++u) {
                int q = p + u;
                int qc = (q < e4) ? q : (e4 - 1);
                qidx[u] = __builtin_amdgcn_readfirstlane(elist[qc]);
            }
            unsigned short vb[8];
#pragma unroll
            for (int u = 0; u < 8; ++u)
                vb[u] = hin[((size_t)qidx[u] << 6) + lane];
            __builtin_amdgcn_sched_barrier(0);
#pragma unroll
            for (int u = 0; u < 8; ++u) {
                int q = p + u;
                float t = (q < e4) ? bf16_f(vb[u]) : 0.f;
                S0 += t;
                S1 += (q >= e1) ? t : 0.f;
                S2 += (q >= e2) ? t : 0.f;
                S3 += (q >= e3) ? t : 0.f;
            }
        }

        int c0 = e1 - e0, c1 = e2 - e1, c2 = e3 - e2, c3 = e4 - e3;
        float a0 = (S0 - S1) * ((c0 > 0) ? 1.0f / (float)c0 : 0.f);
        float a1 = (S1 - S2) * ((c1 > 0) ? 1.0f / (float)c1 : 0.f);
        float a2 = (S2 - S3) * ((c2 > 0) ? 1.0f / (float)c2 : 0.f);
        float a3 = S3 * ((c3 > 0) ? 1.0f / (float)c3 : 0.f);
        Arow[0   + sw] = rne_bf16(a0);
        Arow[64  + sw] = rne_bf16(a1);
        Arow[128 + sw] = rne_bf16(a2);
        Arow[192 + sw] = rne_bf16(a3);
        Arow[256 + sw] = selfb;
    }
    __syncthreads();

    // phase 2: C[32 x 64] = A[32 x 320] * W[320 x 64] via mfma_f32_16x16x32_bf16.
    const int mt = wv & 1;
    const int ntb = (wv >> 1) << 1;
    const int nloc = mt * 16 + (lane & 15);
    f32x4 acc0 = {0.f, 0.f, 0.f, 0.f};
    f32x4 acc1 = {0.f, 0.f, 0.f, 0.f};
    const unsigned short* wp0 = Wp + ((size_t)(ntb * 10) * 64 + lane) * 8;
    const unsigned short* wp1 = Wp + ((size_t)((ntb + 1) * 10) * 64 + lane) * 8;
#pragma unroll 2
    for (int ks = 0; ks < 10; ++ks) {
        int kc = ks * 4 + (lane >> 4);
        int swz = (kc & ~7) | ((kc & 7) ^ (lane & 7));
        short8 a = *reinterpret_cast<const short8*>(&A2[nloc * KDIM + swz * 8]);
        short8 b0 = *reinterpret_cast<const short8*>(&wp0[ks * 512]);
        short8 b1 = *reinterpret_cast<const short8*>(&wp1[ks * 512]);
        acc0 = __builtin_amdgcn_mfma_f32_16x16x32_bf16(a, b0, acc0, 0, 0, 0);
        acc1 = __builtin_amdgcn_mfma_f32_16x16x32_bf16(a, b1, acc1, 0, 0, 0);
    }
    const int h0 = ntb * 16 + (lane & 15);
    const int nr = tile + mt * 16 + ((lane >> 4) << 2);
    const float bb0 = bias[h0];
    const float bb1 = bias[h0 + 16];
#pragma unroll
    for (int r = 0; r < 4; ++r) {
        int n = nr + r;
        if (n < nN) {
            hout[(size_t)n * 64 + h0]      = rne_bf16(fmaxf(acc0[r] + bb0, 0.f));
            hout[(size_t)n * 64 + h0 + 16] = rne_bf16(fmaxf(acc1[r] + bb1, 0.f));
        }
    }
}

// ---------------- fused mean-pool + MLP ----------------

__global__ void k_poolmlp(const unsigned short* __restrict__ h,
                          const int* __restrict__ gstart,
                          const float* __restrict__ w1, const float* __restrict__ b1,
                          const float* __restrict__ w2, const float* __restrict__ b2,
                          float* __restrict__ out) {
    __shared__ float red[4][64];
    __shared__ float sg[64];
    __shared__ float sh[64];
    int g = blockIdx.x;
    int t = threadIdx.x;
    int f = t & 63;
    int sl = t >> 6;
    int s = gstart[g], e = gstart[g + 1];
    float acc = 0.f;
    for (int n = s + sl; n < e; n += 4)
        acc += bf16_f(h[(size_t)n * 64 + f]);
    red[sl][f] = acc;
    __syncthreads();
    if (sl == 0) {
        int c = e - s;
        float m = (red[0][f] + red[1][f] + red[2][f] + red[3][f]) /
                  (float)((c > 0) ? c : 1);
        sg[f] = m;
    }
    __syncthreads();
    if (sl == 0) {
        float a = b1[f];
#pragma unroll 16
        for (int k = 0; k < 64; ++k) a += sg[k] * w1[k * 64 + f];
        sh[f] = fmaxf(a, 0.f);
    }
    __syncthreads();
    if (t < 10) {
        float o = b2[t];
#pragma unroll 16
        for (int k = 0; k < 64; ++k) o += sh[k] * w2[k * 10 + t];
        out[g * 10 + t] = o;
    }
}

// ---------------- launch ----------------

extern "C" void kernel_launch(void* const* d_in, const int* in_sizes, int n_in,
                              void* d_out, int out_size, void* d_ws, size_t ws_size,
                              hipStream_t stream) {
    const float* x     = (const float*)d_in[0];
    const int*   ei    = (const int*)d_in[1];
    const int*   et    = (const int*)d_in[2];
    const int*   batch = (const int*)d_in[3];
    const float* W1    = (const float*)d_in[4];
    const float* root1 = (const float*)d_in[5];
    const float* b1    = (const float*)d_in[6];
    const float* Wl    = (const float*)d_in[7];
    const float* rootl = (const float*)d_in[8];
    const float* bl    = (const float*)d_in[9];
    const float* l1w   = (const float*)d_in[10];
    const float* l1b   = (const float*)d_in[11];
    const float* l2w   = (const float*)d_in[12];
    const float* l2b   = (const float*)d_in[13];
    float* out = (float*)d_out;

    const int N = in_sizes[3];
    const int E = in_sizes[2];
    const int G = out_size / 10;
    const int M = 4 * N;

    const int* src = ei;
    const int* dst = ei + E;

    char* base = (char*)d_ws;
    size_t off = 0;
    auto carve = [&](size_t bytes) {
        char* p = base + off;
        off = (off + bytes + 511) & ~(size_t)511;
        return p;
    };
    int*   cnt4    = (int*)carve((size_t)M * 4);
    int*   start4  = (int*)carve((size_t)(M + 1) * 4);
    int*   rank    = (int*)carve((size_t)E * 4);
    int*   elist   = (int*)carve((size_t)E * 4);
    int*   bsum    = (int*)carve(512 * 4);
    int*   boff    = (int*)carve(512 * 4);
    unsigned short* Wpack = (unsigned short*)carve((size_t)3 * 320 * 64 * 2);
    unsigned short* xb    = (unsigned short*)carve((size_t)N * 64 * 2);
    unsigned short* hb_a  = (unsigned short*)carve((size_t)N * 64 * 2);
    unsigned short* hb_b  = (unsigned short*)carve((size_t)N * 64 * 2);
    int*   gstart  = (int*)carve((size_t)(G + 1) * 4);
    (void)ws_size;

    hipMemsetAsync(cnt4, 0, (size_t)M * 4, stream);

    k_count<<<(E + 255) / 256, 256, 0, stream>>>(dst, et, cnt4, rank, E);

    int nb = (M + 1023) / 1024;
    k_scan1<<<nb, 256, 0, stream>>>(cnt4, start4, bsum, M);
    k_scan2<<<1, 512, 0, stream>>>(bsum, boff, nb);
    k_scan3<<<(M + 1 + 255) / 256, 256, 0, stream>>>(start4, boff, M, E);
    k_fill<<<(E + 255) / 256, 256, 0, stream>>>(src, dst, et, start4, rank, elist, E);

    const int ncvt = (N * 64 / 4 + 255) / 256;
    const int nwp  = (3 * 320 * 64 + 255) / 256;
    const int ngb  = (N + 255) / 256;
    k_prep<<<ncvt + nwp + ngb, 256, 0, stream>>>(x, xb, ncvt, W1, root1, Wl, rootl,
                                                 Wpack, nwp, batch, gstart, N, G);

    const int cb = (N + TILE - 1) / TILE;
    const int WSTRIDE = 320 * 64;
    k_conv<<<cb, 256, 0, stream>>>(xb,   hb_a, elist, start4, Wpack,               b1,      N);
    k_conv<<<cb, 256, 0, stream>>>(hb_a, hb_b, elist, start4, Wpack + WSTRIDE,     bl,      N);
    k_conv<<<cb, 256, 0, stream>>>(hb_b, hb_a, elist, start4, Wpack + 2 * WSTRIDE, bl + 64, N);

    k_poolmlp<<<G, 256, 0, stream>>>(hb_a, gstart, l1w, l1b, l2w, l2b, out);
}

// Round 10
// 334.726 us; speedup vs baseline: 6.9080x; 1.0293x over previous
//
#include <hip/hip_runtime.h>

#define TILE 32
#define KDIM 320

typedef __attribute__((ext_vector_type(8))) short short8;
typedef __attribute__((ext_vector_type(4))) float f32x4;

__device__ inline unsigned short rne_bf16(float f) {
    union { float f; unsigned u; } x;
    x.f = f;
    unsigned r = (x.u + 0x7FFF + ((x.u >> 16) & 1)) >> 16;
    return (unsigned short)r;
}

__device__ inline float bf16_f(unsigned short v) {
    union { unsigned u; float f; } x;
    x.u = ((unsigned)v) << 16;
    return x.f;
}

// scalar {1.0f, 0.0f} mask in an SGPR (condition is wave-uniform)
#define SMASK(cond) __int_as_float(__builtin_amdgcn_readfirstlane((cond) ? 0x3f800000 : 0))

// ---------------- CSR build ----------------

__global__ void k_count(const int* __restrict__ dst, const int* __restrict__ typ,
                        int* __restrict__ cnt4, int* __restrict__ rank, int E) {
    int e = blockIdx.x * 256 + threadIdx.x;
    if (e < E) {
        int seg = dst[e] * 4 + typ[e];
        rank[e] = atomicAdd(&cnt4[seg], 1);
    }
}

__global__ void k_scan1(const int* __restrict__ in, int* __restrict__ out,
                        int* __restrict__ bsum, int M) {
    __shared__ int s[256];
    int t = threadIdx.x;
    int base = blockIdx.x * 1024 + t * 4;
    int v0 = (base + 0 < M) ? in[base + 0] : 0;
    int v1 = (base + 1 < M) ? in[base + 1] : 0;
    int v2 = (base + 2 < M) ? in[base + 2] : 0;
    int v3 = (base + 3 < M) ? in[base + 3] : 0;
    int ts = v0 + v1 + v2 + v3;
    s[t] = ts;
    __syncthreads();
    for (int off = 1; off < 256; off <<= 1) {
        int x = (t >= off) ? s[t - off] : 0;
        __syncthreads();
        s[t] += x;
        __syncthreads();
    }
    int excl = (t == 0) ? 0 : s[t - 1];
    if (t == 255) bsum[blockIdx.x] = s[255];
    if (base + 0 < M) out[base + 0] = excl;
    if (base + 1 < M) out[base + 1] = excl + v0;
    if (base + 2 < M) out[base + 2] = excl + v0 + v1;
    if (base + 3 < M) out[base + 3] = excl + v0 + v1 + v2;
}

__global__ void k_scan2(const int* __restrict__ bsum, int* __restrict__ boff, int nb) {
    __shared__ int s[512];
    int t = threadIdx.x;
    s[t] = (t < nb) ? bsum[t] : 0;
    __syncthreads();
    for (int off = 1; off < 512; off <<= 1) {
        int x = (t >= off) ? s[t - off] : 0;
        __syncthreads();
        s[t] += x;
        __syncthreads();
    }
    if (t < nb) boff[t] = (t == 0) ? 0 : s[t - 1];
}

__global__ void k_scan3(int* __restrict__ out, const int* __restrict__ boff, int M, int E) {
    int i = blockIdx.x * 256 + threadIdx.x;
    if (i < M) out[i] += boff[i >> 10];
    else if (i == M) out[M] = E;
}

__global__ void k_fill(const int* __restrict__ src, const int* __restrict__ dst,
                       const int* __restrict__ typ, const int* __restrict__ start4,
                       const int* __restrict__ rank, int* __restrict__ elist, int E) {
    int e = blockIdx.x * 256 + threadIdx.x;
    if (e < E) {
        int seg = dst[e] * 4 + typ[e];
        elist[start4[seg] + rank[e]] = src[e];
    }
}

// ---------------- fused prep: x->bf16 | weight pack | graph bounds ----------------

__global__ void k_prep(const float* __restrict__ x, unsigned short* __restrict__ xb, int ncvt,
                       const float* __restrict__ W1, const float* __restrict__ root1,
                       const float* __restrict__ Wl, const float* __restrict__ rootl,
                       unsigned short* __restrict__ Wp, int nwp,
                       const int* __restrict__ batch, int* __restrict__ gstart,
                       int nN, int nG) {
    int b = blockIdx.x;
    if (b < ncvt) {
        int i = (b * 256 + threadIdx.x) * 4;
        float4 v = *reinterpret_cast<const float4*>(&x[i]);
        ushort4 o;
        o.x = rne_bf16(v.x); o.y = rne_bf16(v.y);
        o.z = rne_bf16(v.z); o.w = rne_bf16(v.w);
        *reinterpret_cast<ushort4*>(&xb[i]) = o;
        return;
    }
    b -= ncvt;
    if (b < nwp) {
        int idx = b * 256 + threadIdx.x;
        const int TOT = 3 * 320 * 64;
        if (idx >= TOT) return;
        int j = idx & 7;
        int lane = (idx >> 3) & 63;
        int t = idx >> 9;
        int ks = t % 10;
        int lnt = t / 10;
        int nt = lnt & 3;
        int layer = lnt >> 2;
        int k = ks * 32 + ((lane >> 4) << 3) + j;
        int h = nt * 16 + (lane & 15);
        float v;
        if (k < 256) {
            v = (layer == 0) ? W1[k * 64 + h] : Wl[(layer - 1) * 16384 + k * 64 + h];
        } else {
            v = (layer == 0) ? root1[(k - 256) * 64 + h]
                             : rootl[(layer - 1) * 4096 + (k - 256) * 64 + h];
        }
        Wp[idx] = rne_bf16(v);
        return;
    }
    b -= nwp;
    {
        int n = b * 256 + threadIdx.x;
        if (n >= nN) return;
        int bb = batch[n];
        if (n == 0) {
            for (int g = 0; g <= bb; ++g) gstart[g] = 0;
        } else {
            int bp = batch[n - 1];
            for (int g = bp + 1; g <= bb; ++g) gstart[g] = n;
        }
        if (n == nN - 1) {
            for (int g = bb + 1; g <= nG; ++g) gstart[g] = nN;
        }
    }
}

// ---------------- fused RGCN conv layer (bf16 in / bf16 out) ----------------
// Phase 1: wave-uniform CSR state in SGPRs; 16-deep full gather groups
// (contiguous scalar elist loads -> SMEM merge), then 8-full, then ONE
// predicated 8-tail. Relation routing via scalar-float-mask FMAC (1 VALU).
// A-tile LDS layout: (n, k) at n*320 + (kc&~7)*8 + (((kc&7)^(n&7))*8) + (k&7).

__global__ __launch_bounds__(256, 8) void k_conv(
        const unsigned short* __restrict__ hin, unsigned short* __restrict__ hout,
        const int* __restrict__ elist, const int* __restrict__ start4,
        const unsigned short* __restrict__ Wp, const float* __restrict__ bias, int nN) {
    __shared__ unsigned short A2[TILE * KDIM];  // 20 KB -> 8 blocks/CU
    const int tid = threadIdx.x;
    const int lane = tid & 63;
    const int wvs = __builtin_amdgcn_readfirstlane(tid >> 6);
    const int wv = tid >> 6;
    const int tile = blockIdx.x * TILE;

    for (int jj = 0; jj < 8; ++jj) {
        const int nl = wvs * 8 + jj;
        const int n = tile + nl;
        unsigned short* Arow = &A2[nl * KDIM];
        const int sw = (((lane >> 3) ^ (nl & 7)) << 3) + (lane & 7);
        if (n >= nN) {
#pragma unroll
            for (int seg = 0; seg < 5; ++seg) Arow[seg * 64 + sw] = 0;
            continue;
        }
        const int e0 = __builtin_amdgcn_readfirstlane(start4[n * 4 + 0]);
        const int e1 = __builtin_amdgcn_readfirstlane(start4[n * 4 + 1]);
        const int e2 = __builtin_amdgcn_readfirstlane(start4[n * 4 + 2]);
        const int e3 = __builtin_amdgcn_readfirstlane(start4[n * 4 + 3]);
        const int e4 = __builtin_amdgcn_readfirstlane(start4[n * 4 + 4]);

        unsigned short selfb = hin[((size_t)n << 6) + lane];
        float S0 = 0.f, S1 = 0.f, S2 = 0.f, S3 = 0.f;
        int p = e0;

        // 16-deep full groups
        for (; p + 16 <= e4; p += 16) {
            int qidx[16];
#pragma unroll
            for (int u = 0; u < 16; ++u)
                qidx[u] = __builtin_amdgcn_readfirstlane(elist[p + u]);
            unsigned short vb[16];
#pragma unroll
            for (int u = 0; u < 16; ++u)
                vb[u] = hin[((size_t)qidx[u] << 6) + lane];
            __builtin_amdgcn_sched_barrier(0);
#pragma unroll
            for (int u = 0; u < 16; ++u) {
                float t = bf16_f(vb[u]);
                int q = p + u;
                S0 += t;
                S1 = fmaf(t, SMASK(q >= e1), S1);
                S2 = fmaf(t, SMASK(q >= e2), S2);
                S3 = fmaf(t, SMASK(q >= e3), S3);
            }
        }
        // 8-deep full group (at most one)
        for (; p + 8 <= e4; p += 8) {
            int qidx[8];
#pragma unroll
            for (int u = 0; u < 8; ++u)
                qidx[u] = __builtin_amdgcn_readfirstlane(elist[p + u]);
            unsigned short vb[8];
#pragma unroll
            for (int u = 0; u < 8; ++u)
                vb[u] = hin[((size_t)qidx[u] << 6) + lane];
            __builtin_amdgcn_sched_barrier(0);
#pragma unroll
            for (int u = 0; u < 8; ++u) {
                float t = bf16_f(vb[u]);
                int q = p + u;
                S0 += t;
                S1 = fmaf(t, SMASK(q >= e1), S1);
                S2 = fmaf(t, SMASK(q >= e2), S2);
                S3 = fmaf(t, SMASK(q >= e3), S3);
            }
        }
        // one predicated tail group
        if (p < e4) {
            int qidx[8];
#pragma unroll
            for (int u = 0; u < 8; ++u) {
                int q = p + u;
                int qc = (q < e4) ? q : (e4 - 1);
                qidx[u] = __builtin_amdgcn_readfirstlane(elist[qc]);
            }
            unsigned short vb[8];
#pragma unroll
            for (int u = 0; u < 8; ++u)
                vb[u] = hin[((size_t)qidx[u] << 6) + lane];
            __builtin_amdgcn_sched_barrier(0);
#pragma unroll
            for (int u = 0; u < 8; ++u) {
                int q = p + u;
                float t = bf16_f(vb[u]);
                t *= SMASK(q < e4);
                S0 += t;
                S1 = fmaf(t, SMASK(q >= e1), S1);
                S2 = fmaf(t, SMASK(q >= e2), S2);
                S3 = fmaf(t, SMASK(q >= e3), S3);
            }
        }

        int c0 = e1 - e0, c1 = e2 - e1, c2 = e3 - e2, c3 = e4 - e3;
        float a0 = (S0 - S1) * ((c0 > 0) ? 1.0f / (float)c0 : 0.f);
        float a1 = (S1 - S2) * ((c1 > 0) ? 1.0f / (float)c1 : 0.f);
        float a2 = (S2 - S3) * ((c2 > 0) ? 1.0f / (float)c2 : 0.f);
        float a3 = S3 * ((c3 > 0) ? 1.0f / (float)c3 : 0.f);
        Arow[0   + sw] = rne_bf16(a0);
        Arow[64  + sw] = rne_bf16(a1);
        Arow[128 + sw] = rne_bf16(a2);
        Arow[192 + sw] = rne_bf16(a3);
        Arow[256 + sw] = selfb;
    }
    __syncthreads();

    // phase 2: C[32 x 64] = A[32 x 320] * W[320 x 64] via mfma_f32_16x16x32_bf16.
    const int mt = wv & 1;
    const int ntb = (wv >> 1) << 1;
    const int nloc = mt * 16 + (lane & 15);
    f32x4 acc0 = {0.f, 0.f, 0.f, 0.f};
    f32x4 acc1 = {0.f, 0.f, 0.f, 0.f};
    const unsigned short* wp0 = Wp + ((size_t)(ntb * 10) * 64 + lane) * 8;
    const unsigned short* wp1 = Wp + ((size_t)((ntb + 1) * 10) * 64 + lane) * 8;
#pragma unroll 2
    for (int ks = 0; ks < 10; ++ks) {
        int kc = ks * 4 + (lane >> 4);
        int swz = (kc & ~7) | ((kc & 7) ^ (lane & 7));
        short8 a = *reinterpret_cast<const short8*>(&A2[nloc * KDIM + swz * 8]);
        short8 b0 = *reinterpret_cast<const short8*>(&wp0[ks * 512]);
        short8 b1 = *reinterpret_cast<const short8*>(&wp1[ks * 512]);
        acc0 = __builtin_amdgcn_mfma_f32_16x16x32_bf16(a, b0, acc0, 0, 0, 0);
        acc1 = __builtin_amdgcn_mfma_f32_16x16x32_bf16(a, b1, acc1, 0, 0, 0);
    }
    const int h0 = ntb * 16 + (lane & 15);
    const int nr = tile + mt * 16 + ((lane >> 4) << 2);
    const float bb0 = bias[h0];
    const float bb1 = bias[h0 + 16];
#pragma unroll
    for (int r = 0; r < 4; ++r) {
        int n = nr + r;
        if (n < nN) {
            hout[(size_t)n * 64 + h0]      = rne_bf16(fmaxf(acc0[r] + bb0, 0.f));
            hout[(size_t)n * 64 + h0 + 16] = rne_bf16(fmaxf(acc1[r] + bb1, 0.f));
        }
    }
}

// ---------------- fused mean-pool + MLP ----------------

__global__ void k_poolmlp(const unsigned short* __restrict__ h,
                          const int* __restrict__ gstart,
                          const float* __restrict__ w1, const float* __restrict__ b1,
                          const float* __restrict__ w2, const float* __restrict__ b2,
                          float* __restrict__ out) {
    __shared__ float red[4][64];
    __shared__ float sg[64];
    __shared__ float sh[64];
    int g = blockIdx.x;
    int t = threadIdx.x;
    int f = t & 63;
    int sl = t >> 6;
    int s = gstart[g], e = gstart[g + 1];
    float acc = 0.f;
    for (int n = s + sl; n < e; n += 4)
        acc += bf16_f(h[(size_t)n * 64 + f]);
    red[sl][f] = acc;
    __syncthreads();
    if (sl == 0) {
        int c = e - s;
        float m = (red[0][f] + red[1][f] + red[2][f] + red[3][f]) /
                  (float)((c > 0) ? c : 1);
        sg[f] = m;
    }
    __syncthreads();
    if (sl == 0) {
        float a = b1[f];
#pragma unroll 16
        for (int k = 0; k < 64; ++k) a += sg[k] * w1[k * 64 + f];
        sh[f] = fmaxf(a, 0.f);
    }
    __syncthreads();
    if (t < 10) {
        float o = b2[t];
#pragma unroll 16
        for (int k = 0; k < 64; ++k) o += sh[k] * w2[k * 10 + t];
        out[g * 10 + t] = o;
    }
}

// ---------------- launch ----------------

extern "C" void kernel_launch(void* const* d_in, const int* in_sizes, int n_in,
                              void* d_out, int out_size, void* d_ws, size_t ws_size,
                              hipStream_t stream) {
    const float* x     = (const float*)d_in[0];
    const int*   ei    = (const int*)d_in[1];
    const int*   et    = (const int*)d_in[2];
    const int*   batch = (const int*)d_in[3];
    const float* W1    = (const float*)d_in[4];
    const float* root1 = (const float*)d_in[5];
    const float* b1    = (const float*)d_in[6];
    const float* Wl    = (const float*)d_in[7];
    const float* rootl = (const float*)d_in[8];
    const float* bl    = (const float*)d_in[9];
    const float* l1w   = (const float*)d_in[10];
    const float* l1b   = (const float*)d_in[11];
    const float* l2w   = (const float*)d_in[12];
    const float* l2b   = (const float*)d_in[13];
    float* out = (float*)d_out;

    const int N = in_sizes[3];
    const int E = in_sizes[2];
    const int G = out_size / 10;
    const int M = 4 * N;

    const int* src = ei;
    const int* dst = ei + E;

    char* base = (char*)d_ws;
    size_t off = 0;
    auto carve = [&](size_t bytes) {
        char* p = base + off;
        off = (off + bytes + 511) & ~(size_t)511;
        return p;
    };
    int*   cnt4    = (int*)carve((size_t)M * 4);
    int*   start4  = (int*)carve((size_t)(M + 1) * 4);
    int*   rank    = (int*)carve((size_t)E * 4);
    int*   elist   = (int*)carve((size_t)E * 4);
    int*   bsum    = (int*)carve(512 * 4);
    int*   boff    = (int*)carve(512 * 4);
    unsigned short* Wpack = (unsigned short*)carve((size_t)3 * 320 * 64 * 2);
    unsigned short* xb    = (unsigned short*)carve((size_t)N * 64 * 2);
    unsigned short* hb_a  = (unsigned short*)carve((size_t)N * 64 * 2);
    unsigned short* hb_b  = (unsigned short*)carve((size_t)N * 64 * 2);
    int*   gstart  = (int*)carve((size_t)(G + 1) * 4);
    (void)ws_size;

    hipMemsetAsync(cnt4, 0, (size_t)M * 4, stream);

    k_count<<<(E + 255) / 256, 256, 0, stream>>>(dst, et, cnt4, rank, E);

    int nb = (M + 1023) / 1024;
    k_scan1<<<nb, 256, 0, stream>>>(cnt4, start4, bsum, M);
    k_scan2<<<1, 512, 0, stream>>>(bsum, boff, nb);
    k_scan3<<<(M + 1 + 255) / 256, 256, 0, stream>>>(start4, boff, M, E);
    k_fill<<<(E + 255) / 256, 256, 0, stream>>>(src, dst, et, start4, rank, elist, E);

    const int ncvt = (N * 64 / 4 + 255) / 256;
    const int nwp  = (3 * 320 * 64 + 255) / 256;
    const int ngb  = (N + 255) / 256;
    k_prep<<<ncvt + nwp + ngb, 256, 0, stream>>>(x, xb, ncvt, W1, root1, Wl, rootl,
                                                 Wpack, nwp, batch, gstart, N, G);

    const int cb = (N + TILE - 1) / TILE;
    const int WSTRIDE = 320 * 64;
    k_conv<<<cb, 256, 0, stream>>>(xb,   hb_a, elist, start4, Wpack,               b1,      N);
    k_conv<<<cb, 256, 0, stream>>>(hb_a, hb_b, elist, start4, Wpack + WSTRIDE,     bl,      N);
    k_conv<<<cb, 256, 0, stream>>>(hb_b, hb_a, elist, start4, Wpack + 2 * WSTRIDE, bl + 64, N);

    k_poolmlp<<<G, 256, 0, stream>>>(hb_a, gstart, l1w, l1b, l2w, l2b, out);
}